// Round 10
// baseline (269.959 us; speedup 1.0000x reference)
//
#include <hip/hip_runtime.h>
#include <stdint.h>

#define B_ 4
#define S_ 1024
#define D_ 512
#define H_ 8
#define DH_ 64
#define INNER_ 1536
#define M_ (B_*S_)   // 4096

typedef unsigned short u16;
typedef __attribute__((ext_vector_type(8))) short sh8;      // 8 bf16
typedef __attribute__((ext_vector_type(8))) _Float16 h8;    // 8 f16
typedef __attribute__((ext_vector_type(4))) _Float16 h4;    // 4 f16
typedef __attribute__((ext_vector_type(2))) _Float16 h2f;   // 2 f16
typedef __attribute__((ext_vector_type(4))) float f32x4;

typedef __attribute__((address_space(1))) const void cgv;
typedef __attribute__((address_space(3))) void lv;
__device__ __forceinline__ void gl_lds16(const void* g, void* l) {
  __builtin_amdgcn_global_load_lds((cgv*)g, (lv*)l, 16, 0, 0);
}

__device__ __forceinline__ float bf2f(u16 u) {
  union { unsigned int i; float f; } v; v.i = ((unsigned int)u) << 16; return v.f;
}
__device__ __forceinline__ u16 f2bf(float f) {
  union { float f; unsigned int i; } v; v.f = f;
  unsigned int u = v.i;
  return (u16)((u + 0x7FFFu + ((u >> 16) & 1u)) >> 16);
}
__device__ __forceinline__ u16 f2h(float f) {
  _Float16 h = (_Float16)f;
  return *(u16*)&h;
}

// ---------------- fp32 -> bf16 convert ----------------
__global__ __launch_bounds__(256) void f2b_kernel(const float* __restrict__ in,
                                                  u16* __restrict__ out) {
  int i = (blockIdx.x * 256 + threadIdx.x) * 4;
  float4 v = *(const float4*)(in + i);
  uint2 o;
  o.x = (unsigned int)f2bf(v.x) | ((unsigned int)f2bf(v.y) << 16);
  o.y = (unsigned int)f2bf(v.z) | ((unsigned int)f2bf(v.w) << 16);
  *(uint2*)(out + i) = o;
}

// ---------------- all weight transposes in one launch ----------------
// l1/l2 interleaved into W12t: l1 col j -> row 2j, l2 col j -> row 2j+1.
__global__ __launch_bounds__(256) void transpose_all(
    const float* __restrict__ Wq, const float* __restrict__ Wkv,
    const float* __restrict__ Wo, const float* __restrict__ l1,
    const float* __restrict__ l2, const float* __restrict__ l3,
    u16* __restrict__ Wt1, u16* __restrict__ Wot,
    u16* __restrict__ W12t, u16* __restrict__ l3t)
{
  int i = blockIdx.x;
  const float* in; u16* outp; int K, N, bx, by, rs = 1, ra = 0;
  if (i < 64)       { in = Wq;  outp = Wt1;              K = 512;  N = 512;           bx = i & 7;  by = i >> 3; }
  else if (i < 192) { in = Wkv; outp = Wt1 + 512 * 512;  K = 512;  N = 1024; i -= 64; bx = i & 15; by = i >> 4; }
  else if (i < 256) { in = Wo;  outp = Wot;              K = 512;  N = 512;  i -= 192; bx = i & 7;  by = i >> 3; }
  else if (i < 448) { in = l1;  outp = W12t;             K = 512;  N = 1536; i -= 256; bx = i % 24; by = i / 24; rs = 2; ra = 0; }
  else if (i < 640) { in = l2;  outp = W12t;             K = 512;  N = 1536; i -= 448; bx = i % 24; by = i / 24; rs = 2; ra = 1; }
  else              { in = l3;  outp = l3t;              K = 1536; N = 512;  i -= 640; bx = i & 7;  by = i >> 3; }

  __shared__ u16 tile[64][65];
  int tx = threadIdx.x & 63, ty = threadIdx.x >> 6;
  int n0 = bx * 64, k0 = by * 64;
  #pragma unroll
  for (int t = 0; t < 16; t++) {
    int k = ty + t * 4;
    tile[k][tx] = f2bf(in[(size_t)(k0 + k) * N + n0 + tx]);
  }
  __syncthreads();
  #pragma unroll
  for (int t = 0; t < 16; t++) {
    int n = ty + t * 4;
    outp[(size_t)((n0 + n) * rs + ra) * K + k0 + tx] = tile[tx][n];
  }
}

// ---------------- 128x128 GEMM, glds staging ----------------
// EPI 1: qkv scatter (+biases), q/k/v stored f16
// EPI 3: silu-fused FFN-up: interleaved l1/l2 cols; writes g[M, N/2] bf16
template<int EPI>
__global__ __launch_bounds__(256) void gemm_bt(
    const u16* __restrict__ A, const u16* __restrict__ Bt,
    int M, int N, int K,
    const float* __restrict__ bias0, const float* __restrict__ bias1,
    u16* __restrict__ outU,
    u16* __restrict__ qo, u16* __restrict__ ko_, u16* __restrict__ vto)
{
  __shared__ u16 As[128 * 32];
  __shared__ u16 Bs[128 * 32];
  int tid = threadIdx.x;
  int gx = blockIdx.x, gy = blockIdx.y;
  int l = tid & 63, w = tid >> 6;
  int l15 = l & 15, quad = l >> 4;
  int wm = (w >> 1) * 64, wn = (w & 1) * 64;
  f32x4 acc[4][4] = {};

  const u16* Ag = A  + (size_t)(gy * 128 + (tid >> 2)) * K + (tid & 3) * 8;
  const u16* Bg = Bt + (size_t)(gx * 128 + (tid >> 2)) * K + (tid & 3) * 8;

  for (int ko = 0; ko < K; ko += 32) {
    __syncthreads();
    gl_lds16(Ag + ko,                  &As[tid * 8]);
    gl_lds16(Ag + (size_t)64 * K + ko, &As[2048 + tid * 8]);
    gl_lds16(Bg + ko,                  &Bs[tid * 8]);
    gl_lds16(Bg + (size_t)64 * K + ko, &Bs[2048 + tid * 8]);
    __syncthreads();
    sh8 af[4], bfr[4];
    #pragma unroll
    for (int mi = 0; mi < 4; mi++)
      af[mi] = *(const sh8*)&As[(wm + mi * 16 + l15) * 32 + quad * 8];
    #pragma unroll
    for (int ni = 0; ni < 4; ni++)
      bfr[ni] = *(const sh8*)&Bs[(wn + ni * 16 + l15) * 32 + quad * 8];
    #pragma unroll
    for (int mi = 0; mi < 4; mi++)
      #pragma unroll
      for (int ni = 0; ni < 4; ni++)
        acc[mi][ni] = __builtin_amdgcn_mfma_f32_16x16x32_bf16(af[mi], bfr[ni], acc[mi][ni], 0, 0, 0);
  }

  #pragma unroll
  for (int mi = 0; mi < 4; mi++) {
    #pragma unroll
    for (int ni = 0; ni < 4; ni++) {
      #pragma unroll
      for (int r = 0; r < 4; r++) {
        int grow = gy * 128 + wm + mi * 16 + quad * 4 + r;
        int gcol = gx * 128 + wn + ni * 16 + l15;
        float v = acc[mi][ni][r];
        if (EPI == 1) {
          int b = grow >> 10, s = grow & 1023;
          if (gcol < 512) {
            int h = gcol >> 6, dh = gcol & 63;
            qo[(((size_t)b * H_ + h) * S_ + s) * DH_ + dh] = f2h(v + bias0[gcol]);
          } else {
            int n2 = gcol - 512;
            int two = n2 >> 9, h = (n2 >> 6) & 7, dh = n2 & 63;
            float vv = v + bias1[n2];
            if (two == 0) ko_[(((size_t)b * H_ + h) * S_ + s) * DH_ + dh] = f2h(vv);
            else          vto[(((size_t)b * H_ + h) * DH_ + dh) * S_ + s] = f2h(vv);
          }
        } else {
          float vp = __shfl_xor(v, 1);
          if ((l15 & 1) == 0) {
            float a = v, b = vp;
            float gv = a / (1.f + __expf(-a)) * b;
            outU[(size_t)grow * (N >> 1) + (gcol >> 1)] = f2bf(gv);
          }
        }
      }
    }
  }
}

// ---------------- 128x64 GEMM for small-N layers (256 blocks, 8 MFMA/iter) ----------------
// EPI 2: +bias0 +auxF(fp32) -> outF ; EPI 4: +auxH(bf16) -> outF
template<int EPI>
__global__ __launch_bounds__(256) void gemm_n64(
    const u16* __restrict__ A, const u16* __restrict__ Bt,
    int M, int N, int K,
    const float* __restrict__ bias0, const float* __restrict__ auxF,
    const u16* __restrict__ auxH, float* __restrict__ outF)
{
  __shared__ u16 As[128 * 32];
  __shared__ u16 Bs[64 * 32];
  int tid = threadIdx.x;
  int gx = blockIdx.x, gy = blockIdx.y;
  int l = tid & 63, w = tid >> 6;
  int l15 = l & 15, quad = l >> 4;
  int wm = (w >> 1) * 64, wn = (w & 1) * 32;
  f32x4 acc[4][2] = {};

  const u16* Ag = A  + (size_t)(gy * 128 + (tid >> 2)) * K + (tid & 3) * 8;
  const u16* Bg = Bt + (size_t)(gx * 64  + (tid >> 2)) * K + (tid & 3) * 8;

  for (int ko = 0; ko < K; ko += 32) {
    __syncthreads();
    gl_lds16(Ag + ko,                  &As[tid * 8]);
    gl_lds16(Ag + (size_t)64 * K + ko, &As[2048 + tid * 8]);
    gl_lds16(Bg + ko,                  &Bs[tid * 8]);
    __syncthreads();
    sh8 af[4], bfr[2];
    #pragma unroll
    for (int mi = 0; mi < 4; mi++)
      af[mi] = *(const sh8*)&As[(wm + mi * 16 + l15) * 32 + quad * 8];
    #pragma unroll
    for (int ni = 0; ni < 2; ni++)
      bfr[ni] = *(const sh8*)&Bs[(wn + ni * 16 + l15) * 32 + quad * 8];
    #pragma unroll
    for (int mi = 0; mi < 4; mi++)
      #pragma unroll
      for (int ni = 0; ni < 2; ni++)
        acc[mi][ni] = __builtin_amdgcn_mfma_f32_16x16x32_bf16(af[mi], bfr[ni], acc[mi][ni], 0, 0, 0);
  }

  #pragma unroll
  for (int mi = 0; mi < 4; mi++) {
    #pragma unroll
    for (int ni = 0; ni < 2; ni++) {
      #pragma unroll
      for (int r = 0; r < 4; r++) {
        int grow = gy * 128 + wm + mi * 16 + quad * 4 + r;
        int gcol = gx * 64 + wn + ni * 16 + l15;
        float v = acc[mi][ni][r];
        if (EPI == 2) v += bias0[gcol] + auxF[(size_t)grow * N + gcol];
        else          v += bf2f(auxH[(size_t)grow * N + gcol]);
        outF[(size_t)grow * N + gcol] = v;
      }
    }
  }
}

// ---------------- sparse attention v7: all-register K/V prefetch rings ----------------
// Scores never touch LDS: each lane's MFMA output IS its 64 e'-values for row l15.
// Z1 = sum(e'), Z2 = 1025 + S2/(2 Z1^2) (S2 = sum(e'^2); w^3 term ~1e-7 rel, dropped).
#define RSTRIDE 1028   // halves; c' row stride (2056 B)
__global__ __launch_bounds__(256, 4) void attn_kernel(
    const u16* __restrict__ q, const u16* __restrict__ kk,
    const u16* __restrict__ vt, u16* __restrict__ attn)
{
  __shared__ u16 scb[16 * RSTRIDE + 256];          // 32.9 KB c' + 512 B sums
  float* sums = (float*)(scb + 16 * RSTRIDE);      // [4 waves][16 rows][2]

  int tid = threadIdx.x;
  int l = tid & 63, w = tid >> 6;
  int l15 = l & 15, quad = l >> 4;
  int blk = blockIdx.x;
  // XCD-aware swizzle: 4 bh per XCD
  int xcd = blk & 7, li = blk >> 3;
  int bh = xcd * 4 + (li & 3);
  int r0 = (li >> 2) << 4;

  const u16* qb = q  + ((size_t)bh * S_ + r0) * DH_;
  const u16* kb = kk + (size_t)bh * S_ * DH_;
  const u16* vb = vt + (size_t)bh * DH_ * S_;

  h8 aq0 = *(const h8*)(qb + l15 * DH_ + quad * 8);
  h8 aq1 = *(const h8*)(qb + l15 * DH_ + 32 + quad * 8);

  // ---- phase A: K register-prefetch ring (4 slots, distance 3)
  h8 kreg[4][2];
  #pragma unroll
  for (int p = 0; p < 3; p++) {
    const u16* kr = kb + (size_t)(((((p << 2) | w) << 4) + l15)) * DH_ + quad * 8;
    kreg[p][0] = *(const h8*)kr;
    kreg[p][1] = *(const h8*)(kr + 32);
  }
  uint32_t kv[32];
  float S1 = 0.f, S2 = 0.f;
  #pragma unroll
  for (int i = 0; i < 16; i++) {
    if (i + 3 < 16) {
      const u16* kr = kb + (size_t)((((((i + 3) << 2) | w) << 4) + l15)) * DH_ + quad * 8;
      kreg[(i + 3) & 3][0] = *(const h8*)kr;
      kreg[(i + 3) & 3][1] = *(const h8*)(kr + 32);
    }
    f32x4 s4 = {};
    s4 = __builtin_amdgcn_mfma_f32_16x16x32_f16(kreg[i & 3][0], aq0, s4, 0, 0, 0);
    s4 = __builtin_amdgcn_mfma_f32_16x16x32_f16(kreg[i & 3][1], aq1, s4, 0, 0, 0);
    float e0 = exp2f(fmaf(s4[0], 0.18033688f, -11.5415603f));   // exp(s/8 - 8)
    float e1 = exp2f(fmaf(s4[1], 0.18033688f, -11.5415603f));
    float e2 = exp2f(fmaf(s4[2], 0.18033688f, -11.5415603f));
    float e3 = exp2f(fmaf(s4[3], 0.18033688f, -11.5415603f));
    S1 += e0 + e1 + e2 + e3;
    S2 += e0 * e0 + e1 * e1 + e2 * e2 + e3 * e3;
    h2f p0; p0[0] = (_Float16)e0; p0[1] = (_Float16)e1;
    h2f p1; p1[0] = (_Float16)e2; p1[1] = (_Float16)e3;
    kv[2 * i]     = __builtin_bit_cast(uint32_t, p0);
    kv[2 * i + 1] = __builtin_bit_cast(uint32_t, p1);
  }
  // intra-wave reduce over quad (lanes l15+16q)
  S1 += __shfl_xor(S1, 16); S1 += __shfl_xor(S1, 32);
  S2 += __shfl_xor(S2, 16); S2 += __shfl_xor(S2, 32);
  if (l < 16) {
    sums[(w * 16 + l15) * 2]     = S1;
    sums[(w * 16 + l15) * 2 + 1] = S2;
  }
  __syncthreads();   // B1
  float Z1 = 0.f, S2t = 0.f;
  #pragma unroll
  for (int ww = 0; ww < 4; ww++) {
    Z1  += sums[(ww * 16 + l15) * 2];
    S2t += sums[(ww * 16 + l15) * 2 + 1];
  }
  float invZ1 = 1.0f / Z1;
  float Z2 = 1025.0f + 0.5f * S2t * invZ1 * invZ1;
  float invZ2 = 1.0f / Z2;

  // c' = exp(w)/Z2 via packed-f16 Horner; write to LDS in phase-A layout
  _Float16 izh = (_Float16)invZ1;
  h2f izv; izv[0] = izh; izv[1] = izh;
  _Float16 z2h = (_Float16)invZ2;
  h2f z2v; z2v[0] = z2h; z2v[1] = z2h;
  h2f onev; onev[0] = (_Float16)1.f; onev[1] = (_Float16)1.f;
  h2f c2v;  c2v[0] = (_Float16)0.5f; c2v[1] = (_Float16)0.5f;
  h2f c6v;  c6v[0] = (_Float16)(1.f/6.f); c6v[1] = (_Float16)(1.f/6.f);
  #pragma unroll
  for (int i = 0; i < 16; i++) {
    int t0 = ((i << 2) | w) << 4;
    uint2 ov;
    #pragma unroll
    for (int hwd = 0; hwd < 2; hwd++) {
      h2f e = __builtin_bit_cast(h2f, kv[2 * i + hwd]);
      h2f wv = e * izv;
      h2f p = wv * c6v + c2v;
      h2f qq = wv * p + onev;
      h2f cm1 = wv * qq;
      h2f cp = cm1 * z2v + z2v;
      (&ov.x)[hwd] = __builtin_bit_cast(uint32_t, cp);
    }
    *(uint2*)(scb + l15 * RSTRIDE + t0 + quad * 4) = ov;
  }
  __syncthreads();   // B2

  // ---- phase E: o = c' @ V; V register-prefetch ring (4 slots, distance 3)
  int n0 = w << 4;
  const u16* crow = scb + l15 * RSTRIDE;
  const u16* vsrc = vb + (size_t)(n0 + l15) * S_ + quad * 8;
  h8 vreg[4];
  vreg[0] = *(const h8*)vsrc;
  vreg[1] = *(const h8*)(vsrc + 32);
  vreg[2] = *(const h8*)(vsrc + 64);
  f32x4 oacc = {};
  #pragma unroll
  for (int kt = 0; kt < 32; kt++) {
    if (kt + 3 < 32)
      vreg[(kt + 3) & 3] = *(const h8*)(vsrc + (kt + 3) * 32);
    h8 ca = *(const h8*)(crow + kt * 32 + quad * 8);
    oacc = __builtin_amdgcn_mfma_f32_16x16x32_f16(ca, vreg[kt & 3], oacc, 0, 0, 0);
  }
  int b = bh >> 3, hh = bh & 7;
  #pragma unroll
  for (int r = 0; r < 4; r++) {
    int rr = quad * 4 + r;
    attn[((size_t)b * S_ + r0 + rr) * D_ + hh * DH_ + n0 + l15] = f2bf(oacc[r]);
  }
}

// ---------------- RMS norm over D per row: fp32 in, bf16 out ----------------
__global__ __launch_bounds__(128) void rms_kernel(const float* __restrict__ in,
                                                  const float* __restrict__ w,
                                                  u16* __restrict__ out) {
  int row = blockIdx.x;
  int tid = threadIdx.x;
  const float* r = in + (size_t)row * D_;
  float v0 = r[tid], v1 = r[tid + 128], v2 = r[tid + 256], v3 = r[tid + 384];
  float s = v0 * v0 + v1 * v1 + v2 * v2 + v3 * v3;
  #pragma unroll
  for (int d = 1; d < 64; d <<= 1) s += __shfl_xor(s, d);
  __shared__ float red[2];
  if ((tid & 63) == 0) red[tid >> 6] = s;
  __syncthreads();
  s = red[0] + red[1];
  float rs = rsqrtf(s * (1.0f / 512.0f) + 1e-6f);
  out[(size_t)row * D_ + tid      ] = f2bf(v0 * rs * w[tid      ]);
  out[(size_t)row * D_ + tid + 128] = f2bf(v1 * rs * w[tid + 128]);
  out[(size_t)row * D_ + tid + 256] = f2bf(v2 * rs * w[tid + 256]);
  out[(size_t)row * D_ + tid + 384] = f2bf(v3 * rs * w[tid + 384]);
}

// ---------------- instance norm: two-stage stats ----------------
__global__ __launch_bounds__(256) void inorm_stats1(const float* __restrict__ y,
                                                    float* __restrict__ part) {
  int b = blockIdx.x, dc = blockIdx.y, sc = blockIdx.z;
  int dl = threadIdx.x & 63, sl = threadIdx.x >> 6;
  int d = dc * 64 + dl;
  const float* yb = y + (size_t)b * S_ * D_ + (size_t)(sc * 64 + sl * 16) * D_ + d;
  float s1 = 0.f, s2 = 0.f;
  #pragma unroll
  for (int i = 0; i < 16; i++) {
    float v = yb[(size_t)i * D_];
    s1 += v; s2 += v * v;
  }
  __shared__ float r1[256], r2[256];
  r1[threadIdx.x] = s1; r2[threadIdx.x] = s2;
  __syncthreads();
  if (sl == 0) {
    s1 = r1[dl] + r1[dl + 64] + r1[dl + 128] + r1[dl + 192];
    s2 = r2[dl] + r2[dl + 64] + r2[dl + 128] + r2[dl + 192];
    float2 p; p.x = s1; p.y = s2;
    *(float2*)&part[(((size_t)(b * 8 + dc) * 64 + dl) * 16 + sc) * 2] = p;
  }
}

__global__ __launch_bounds__(256) void inorm_stats2(const float* __restrict__ part,
                                                    float* __restrict__ stats) {
  int idx = blockIdx.x * 256 + threadIdx.x;   // (b*512+d), 2048 total
  float s1 = 0.f, s2 = 0.f;
  #pragma unroll
  for (int i = 0; i < 16; i++) {
    float2 p = *(const float2*)&part[((size_t)idx * 16 + i) * 2];
    s1 += p.x; s2 += p.y;
  }
  float m = s1 * (1.f / 1024.f);
  float var = s2 * (1.f / 1024.f) - m * m;
  stats[idx * 2]     = m;
  stats[idx * 2 + 1] = rsqrtf(var + 1e-5f);
}

__global__ __launch_bounds__(256) void inorm_apply(const float* __restrict__ y,
                                                   const float* __restrict__ stats,
                                                   const float* __restrict__ w,
                                                   const float* __restrict__ bias,
                                                   float* __restrict__ out) {
  int row = blockIdx.x;
  int b = row >> 10;
  int tid = threadIdx.x;
  #pragma unroll
  for (int i = 0; i < 2; i++) {
    int d = tid + i * 256;
    float m  = stats[((size_t)b * D_ + d) * 2];
    float rs = stats[((size_t)b * D_ + d) * 2 + 1];
    float v = y[(size_t)row * D_ + d];
    out[(size_t)row * D_ + d] = (v - m) * rs * w[d] + bias[d];
  }
}

// ---------------- launch ----------------
extern "C" void kernel_launch(void* const* d_in, const int* in_sizes, int n_in,
                              void* d_out, int out_size, void* d_ws, size_t ws_size,
                              hipStream_t stream) {
  const float* x    = (const float*)d_in[0];
  const float* Wq   = (const float*)d_in[1];
  const float* bq   = (const float*)d_in[2];
  const float* Wkv  = (const float*)d_in[3];
  const float* bkv  = (const float*)d_in[4];
  const float* Wo   = (const float*)d_in[5];
  const float* bo   = (const float*)d_in[6];
  const float* rmsw = (const float*)d_in[7];
  const float* l1   = (const float*)d_in[8];
  const float* l2   = (const float*)d_in[9];
  const float* l3   = (const float*)d_in[10];
  const float* inw  = (const float*)d_in[11];
  const float* inb  = (const float*)d_in[12];
  float* out = (float*)d_out;

  char* ws = (char*)d_ws;
  size_t off = 0;
  auto alloc = [&](size_t n) { char* p = ws + off; off += (n + 255) & ~(size_t)255; return p; };
  u16*  xb   = (u16*) alloc((size_t)M_ * D_ * 2);
  u16*  Wt1  = (u16*) alloc((size_t)1536 * 512 * 2);
  u16*  Wot  = (u16*) alloc((size_t)512 * 512 * 2);
  u16*  W12t = (u16*) alloc((size_t)3072 * 512 * 2);   // interleaved l1/l2
  u16*  l3t  = (u16*) alloc((size_t)512 * 1536 * 2);
  u16*  qb   = (u16*) alloc((size_t)M_ * D_ * 2);      // f16 [B,H,S,DH]
  u16*  kb   = (u16*) alloc((size_t)M_ * D_ * 2);      // f16 [B,H,S,DH]
  u16*  vtb  = (u16*) alloc((size_t)M_ * D_ * 2);      // f16 [B,H,DH,S]
  u16*  attn = (u16*) alloc((size_t)M_ * D_ * 2);      // bf16 [B,S,D]
  float* tmpF = (float*)alloc((size_t)M_ * D_ * 4);
  u16*  hhat = (u16*) alloc((size_t)M_ * D_ * 2);
  u16*  g    = (u16*) alloc((size_t)M_ * INNER_ * 2);
  float* part  = (float*)alloc((size_t)B_ * D_ * 16 * 2 * 4);
  float* stats = (float*)alloc((size_t)B_ * D_ * 2 * 4);

  transpose_all<<<832, 256, 0, stream>>>(Wq, Wkv, Wo, l1, l2, l3, Wt1, Wot, W12t, l3t);
  f2b_kernel<<<2048, 256, 0, stream>>>(x, xb);

  gemm_bt<1><<<dim3(12, 32), 256, 0, stream>>>(xb, Wt1, M_, 1536, 512,
      bq, bkv, nullptr, qb, kb, vtb);

  attn_kernel<<<2048, 256, 0, stream>>>(qb, kb, vtb, attn);

  gemm_n64<2><<<dim3(8, 32), 256, 0, stream>>>(attn, Wot, M_, 512, 512,
      bo, x, nullptr, tmpF);

  rms_kernel<<<4096, 128, 0, stream>>>(tmpF, rmsw, hhat);

  // FFN up + silu fused: writes g [M, 1536] directly
  gemm_bt<3><<<dim3(24, 32), 256, 0, stream>>>(hhat, W12t, M_, 3072, 512,
      nullptr, nullptr, g, nullptr, nullptr, nullptr);

  gemm_n64<4><<<dim3(8, 32), 256, 0, stream>>>(g, l3t, M_, 512, 1536,
      nullptr, nullptr, hhat, tmpF);

  inorm_stats1<<<dim3(4, 8, 16), 256, 0, stream>>>(tmpF, part);
  inorm_stats2<<<8, 256, 0, stream>>>(part, stats);
  inorm_apply<<<4096, 256, 0, stream>>>(tmpF, stats, inw, inb, out);
}

// Round 11
// 227.767 us; speedup vs baseline: 1.1852x; 1.1852x over previous
//
#include <hip/hip_runtime.h>
#include <stdint.h>

#define B_ 4
#define S_ 1024
#define D_ 512
#define H_ 8
#define DH_ 64
#define INNER_ 1536
#define M_ (B_*S_)   // 4096

typedef unsigned short u16;
typedef __attribute__((ext_vector_type(8))) short sh8;      // 8 bf16
typedef __attribute__((ext_vector_type(8))) _Float16 h8;    // 8 f16
typedef __attribute__((ext_vector_type(4))) _Float16 h4;    // 4 f16
typedef __attribute__((ext_vector_type(2))) _Float16 h2f;   // 2 f16
typedef __attribute__((ext_vector_type(4))) float f32x4;

typedef __attribute__((address_space(1))) const void cgv;
typedef __attribute__((address_space(3))) void lv;
__device__ __forceinline__ void gl_lds16(const void* g, void* l) {
  __builtin_amdgcn_global_load_lds((cgv*)g, (lv*)l, 16, 0, 0);
}
// wait until <=N vm ops outstanding; ignore lgkm(15)/exp(7)
#define WAITVM(N) __builtin_amdgcn_s_waitcnt(0x0F70 | (N))

__device__ __forceinline__ float bf2f(u16 u) {
  union { unsigned int i; float f; } v; v.i = ((unsigned int)u) << 16; return v.f;
}
__device__ __forceinline__ u16 f2bf(float f) {
  union { float f; unsigned int i; } v; v.f = f;
  unsigned int u = v.i;
  return (u16)((u + 0x7FFFu + ((u >> 16) & 1u)) >> 16);
}
__device__ __forceinline__ u16 f2h(float f) {
  _Float16 h = (_Float16)f;
  return *(u16*)&h;
}

// ---------------- fp32 -> bf16 convert ----------------
__global__ __launch_bounds__(256) void f2b_kernel(const float* __restrict__ in,
                                                  u16* __restrict__ out) {
  int i = (blockIdx.x * 256 + threadIdx.x) * 4;
  float4 v = *(const float4*)(in + i);
  uint2 o;
  o.x = (unsigned int)f2bf(v.x) | ((unsigned int)f2bf(v.y) << 16);
  o.y = (unsigned int)f2bf(v.z) | ((unsigned int)f2bf(v.w) << 16);
  *(uint2*)(out + i) = o;
}

// ---------------- all weight transposes in one launch ----------------
// l1/l2 interleaved into W12t: l1 col j -> row 2j, l2 col j -> row 2j+1.
__global__ __launch_bounds__(256) void transpose_all(
    const float* __restrict__ Wq, const float* __restrict__ Wkv,
    const float* __restrict__ Wo, const float* __restrict__ l1,
    const float* __restrict__ l2, const float* __restrict__ l3,
    u16* __restrict__ Wt1, u16* __restrict__ Wot,
    u16* __restrict__ W12t, u16* __restrict__ l3t)
{
  int i = blockIdx.x;
  const float* in; u16* outp; int K, N, bx, by, rs = 1, ra = 0;
  if (i < 64)       { in = Wq;  outp = Wt1;              K = 512;  N = 512;           bx = i & 7;  by = i >> 3; }
  else if (i < 192) { in = Wkv; outp = Wt1 + 512 * 512;  K = 512;  N = 1024; i -= 64; bx = i & 15; by = i >> 4; }
  else if (i < 256) { in = Wo;  outp = Wot;              K = 512;  N = 512;  i -= 192; bx = i & 7;  by = i >> 3; }
  else if (i < 448) { in = l1;  outp = W12t;             K = 512;  N = 1536; i -= 256; bx = i % 24; by = i / 24; rs = 2; ra = 0; }
  else if (i < 640) { in = l2;  outp = W12t;             K = 512;  N = 1536; i -= 448; bx = i % 24; by = i / 24; rs = 2; ra = 1; }
  else              { in = l3;  outp = l3t;              K = 1536; N = 512;  i -= 640; bx = i & 7;  by = i >> 3; }

  __shared__ u16 tile[64][65];
  int tx = threadIdx.x & 63, ty = threadIdx.x >> 6;
  int n0 = bx * 64, k0 = by * 64;
  #pragma unroll
  for (int t = 0; t < 16; t++) {
    int k = ty + t * 4;
    tile[k][tx] = f2bf(in[(size_t)(k0 + k) * N + n0 + tx]);
  }
  __syncthreads();
  #pragma unroll
  for (int t = 0; t < 16; t++) {
    int n = ty + t * 4;
    outp[(size_t)((n0 + n) * rs + ra) * K + k0 + tx] = tile[tx][n];
  }
}

// ---------------- 128x128 GEMM, glds staging ----------------
// EPI 1: qkv scatter (+biases), q/k/v stored f16
// EPI 3: silu-fused FFN-up: interleaved l1/l2 cols; writes g[M, N/2] bf16
template<int EPI>
__global__ __launch_bounds__(256) void gemm_bt(
    const u16* __restrict__ A, const u16* __restrict__ Bt,
    int M, int N, int K,
    const float* __restrict__ bias0, const float* __restrict__ bias1,
    u16* __restrict__ outU,
    u16* __restrict__ qo, u16* __restrict__ ko_, u16* __restrict__ vto)
{
  __shared__ u16 As[128 * 32];
  __shared__ u16 Bs[128 * 32];
  int tid = threadIdx.x;
  int gx = blockIdx.x, gy = blockIdx.y;
  int l = tid & 63, w = tid >> 6;
  int l15 = l & 15, quad = l >> 4;
  int wm = (w >> 1) * 64, wn = (w & 1) * 64;
  f32x4 acc[4][4] = {};

  const u16* Ag = A  + (size_t)(gy * 128 + (tid >> 2)) * K + (tid & 3) * 8;
  const u16* Bg = Bt + (size_t)(gx * 128 + (tid >> 2)) * K + (tid & 3) * 8;

  for (int ko = 0; ko < K; ko += 32) {
    __syncthreads();
    gl_lds16(Ag + ko,                  &As[tid * 8]);
    gl_lds16(Ag + (size_t)64 * K + ko, &As[2048 + tid * 8]);
    gl_lds16(Bg + ko,                  &Bs[tid * 8]);
    gl_lds16(Bg + (size_t)64 * K + ko, &Bs[2048 + tid * 8]);
    __syncthreads();
    sh8 af[4], bfr[4];
    #pragma unroll
    for (int mi = 0; mi < 4; mi++)
      af[mi] = *(const sh8*)&As[(wm + mi * 16 + l15) * 32 + quad * 8];
    #pragma unroll
    for (int ni = 0; ni < 4; ni++)
      bfr[ni] = *(const sh8*)&Bs[(wn + ni * 16 + l15) * 32 + quad * 8];
    #pragma unroll
    for (int mi = 0; mi < 4; mi++)
      #pragma unroll
      for (int ni = 0; ni < 4; ni++)
        acc[mi][ni] = __builtin_amdgcn_mfma_f32_16x16x32_bf16(af[mi], bfr[ni], acc[mi][ni], 0, 0, 0);
  }

  #pragma unroll
  for (int mi = 0; mi < 4; mi++) {
    #pragma unroll
    for (int ni = 0; ni < 4; ni++) {
      #pragma unroll
      for (int r = 0; r < 4; r++) {
        int grow = gy * 128 + wm + mi * 16 + quad * 4 + r;
        int gcol = gx * 128 + wn + ni * 16 + l15;
        float v = acc[mi][ni][r];
        if (EPI == 1) {
          int b = grow >> 10, s = grow & 1023;
          if (gcol < 512) {
            int h = gcol >> 6, dh = gcol & 63;
            qo[(((size_t)b * H_ + h) * S_ + s) * DH_ + dh] = f2h(v + bias0[gcol]);
          } else {
            int n2 = gcol - 512;
            int two = n2 >> 9, h = (n2 >> 6) & 7, dh = n2 & 63;
            float vv = v + bias1[n2];
            if (two == 0) ko_[(((size_t)b * H_ + h) * S_ + s) * DH_ + dh] = f2h(vv);
            else          vto[(((size_t)b * H_ + h) * DH_ + dh) * S_ + s] = f2h(vv);
          }
        } else {
          float vp = __shfl_xor(v, 1);
          if ((l15 & 1) == 0) {
            float a = v, b = vp;
            float gv = a / (1.f + __expf(-a)) * b;
            outU[(size_t)grow * (N >> 1) + (gcol >> 1)] = f2bf(gv);
          }
        }
      }
    }
  }
}

// ---------------- 128x64 GEMM for small-N layers (256 blocks, 8 MFMA/iter) ----------------
// EPI 2: +bias0 +auxF(fp32) -> outF
// EPI 4: +auxH(bf16) -> outF, fused per-column partial sums -> part (for instance norm)
template<int EPI>
__global__ __launch_bounds__(256) void gemm_n64(
    const u16* __restrict__ A, const u16* __restrict__ Bt,
    int M, int N, int K,
    const float* __restrict__ bias0, const float* __restrict__ auxF,
    const u16* __restrict__ auxH, float* __restrict__ outF,
    float* __restrict__ part)
{
  __shared__ u16 As[128 * 32];
  __shared__ u16 Bs[64 * 32];
  __shared__ float ss1[4][2][16], ss2[4][2][16];
  int tid = threadIdx.x;
  int gx = blockIdx.x, gy = blockIdx.y;
  int l = tid & 63, w = tid >> 6;
  int l15 = l & 15, quad = l >> 4;
  int wm = (w >> 1) * 64, wn = (w & 1) * 32;
  f32x4 acc[4][2] = {};

  const u16* Ag = A  + (size_t)(gy * 128 + (tid >> 2)) * K + (tid & 3) * 8;
  const u16* Bg = Bt + (size_t)(gx * 64  + (tid >> 2)) * K + (tid & 3) * 8;

  for (int ko = 0; ko < K; ko += 32) {
    __syncthreads();
    gl_lds16(Ag + ko,                  &As[tid * 8]);
    gl_lds16(Ag + (size_t)64 * K + ko, &As[2048 + tid * 8]);
    gl_lds16(Bg + ko,                  &Bs[tid * 8]);
    __syncthreads();
    sh8 af[4], bfr[2];
    #pragma unroll
    for (int mi = 0; mi < 4; mi++)
      af[mi] = *(const sh8*)&As[(wm + mi * 16 + l15) * 32 + quad * 8];
    #pragma unroll
    for (int ni = 0; ni < 2; ni++)
      bfr[ni] = *(const sh8*)&Bs[(wn + ni * 16 + l15) * 32 + quad * 8];
    #pragma unroll
    for (int mi = 0; mi < 4; mi++)
      #pragma unroll
      for (int ni = 0; ni < 2; ni++)
        acc[mi][ni] = __builtin_amdgcn_mfma_f32_16x16x32_bf16(af[mi], bfr[ni], acc[mi][ni], 0, 0, 0);
  }

  float cs1[2] = {0.f, 0.f}, cs2[2] = {0.f, 0.f};
  #pragma unroll
  for (int mi = 0; mi < 4; mi++) {
    #pragma unroll
    for (int ni = 0; ni < 2; ni++) {
      #pragma unroll
      for (int r = 0; r < 4; r++) {
        int grow = gy * 128 + wm + mi * 16 + quad * 4 + r;
        int gcol = gx * 64 + wn + ni * 16 + l15;
        float v = acc[mi][ni][r];
        if (EPI == 2) v += bias0[gcol] + auxF[(size_t)grow * N + gcol];
        else          v += bf2f(auxH[(size_t)grow * N + gcol]);
        outF[(size_t)grow * N + gcol] = v;
        if (EPI == 4) { cs1[ni] += v; cs2[ni] += v * v; }
      }
    }
  }
  if (EPI == 4) {
    // reduce over quads (rows) -> per-wave 64-row column sums
    #pragma unroll
    for (int ni = 0; ni < 2; ni++) {
      cs1[ni] += __shfl_xor(cs1[ni], 16); cs1[ni] += __shfl_xor(cs1[ni], 32);
      cs2[ni] += __shfl_xor(cs2[ni], 16); cs2[ni] += __shfl_xor(cs2[ni], 32);
    }
    if (l < 16) {
      ss1[w][0][l15] = cs1[0]; ss1[w][1][l15] = cs1[1];
      ss2[w][0][l15] = cs2[0]; ss2[w][1][l15] = cs2[1];
    }
    __syncthreads();
    if (tid < 64) {
      int wsel = (tid >> 5) & 1, ni = (tid >> 4) & 1, cl = tid & 15;
      float s1 = ss1[wsel][ni][cl] + ss1[wsel + 2][ni][cl];
      float s2 = ss2[wsel][ni][cl] + ss2[wsel + 2][ni][cl];
      int col = gx * 64 + wsel * 32 + ni * 16 + cl;
      int b = gy >> 3, seg = gy & 7;
      float2 p; p.x = s1; p.y = s2;
      *(float2*)&part[((size_t)(b * 512 + col) * 8 + seg) * 2] = p;
    }
  }
}

// ---------------- sparse attention v8: DMA K/V rings + register-sum softmax ----------------
// Z1 = sum e', Z2 = 1025 + S2/(2 Z1^2) (maskless Taylor softmax2, validated r8/r10).
#define RSTRIDE 1032                 // halves; c' row stride (2064 B)
#define STAGE_H (16 * RSTRIDE)       // staging region offset, halves
__global__ __launch_bounds__(256, 3) void attn_kernel(
    const u16* __restrict__ q, const u16* __restrict__ kk,
    const u16* __restrict__ vt, u16* __restrict__ attn)
{
  // c' 33,024B + staging 16,384B + sums 512B = 49,920B -> 3 blocks/CU
  __shared__ u16 scb[16 * RSTRIDE + 4 * 2048 + 256];
  float* sums = (float*)(scb + 16 * RSTRIDE + 4 * 2048);

  int tid = threadIdx.x;
  int l = tid & 63, w = tid >> 6;
  int l15 = l & 15, quad = l >> 4;
  int blk = blockIdx.x;
  // XCD-aware swizzle: 4 bh per XCD
  int xcd = blk & 7, li = blk >> 3;
  int bh = xcd * 4 + (li & 3);
  int r0 = (li >> 2) << 4;

  const u16* qb = q  + ((size_t)bh * S_ + r0) * DH_;
  const u16* kb = kk + (size_t)bh * S_ * DH_;
  const u16* vb = vt + (size_t)bh * DH_ * S_;

  int ws = STAGE_H + w * 2048;     // per-wave private staging base (halves)
  int lr = l >> 2, lc = l & 3;

  h8 aq0 = *(const h8*)(qb + l15 * DH_ + quad * 8);
  h8 aq1 = *(const h8*)(qb + l15 * DH_ + 32 + quad * 8);

  // ---- phase A: K DMA-staged 2-deep; e' kept in registers; S1,S2 accumulated
  uint32_t kv[32];
  float S1 = 0.f, S2 = 0.f;
  #pragma unroll
  for (int i = 0; i < 16; i++) {
    if (i == 0) {
      const u16* src = kb + (size_t)((w << 4) + lr) * DH_ + lc * 8;
      gl_lds16(src,      &scb[ws + l * 8]);
      gl_lds16(src + 32, &scb[ws + 512 + l * 8]);
    }
    if (i + 1 < 16) {
      int t0n = (((i + 1) << 2) | w) << 4;
      const u16* src = kb + (size_t)(t0n + lr) * DH_ + lc * 8;
      int sb = ws + ((i + 1) & 1) * 1024;
      gl_lds16(src,      &scb[sb + l * 8]);
      gl_lds16(src + 32, &scb[sb + 512 + l * 8]);
    }
    if (i + 1 < 16) { WAITVM(2); } else { WAITVM(0); }
    int sb = ws + (i & 1) * 1024;
    h8 bk0 = *(const h8*)&scb[sb + l15 * 32 + quad * 8];
    h8 bk1 = *(const h8*)&scb[sb + 512 + l15 * 32 + quad * 8];
    f32x4 s4 = {};
    s4 = __builtin_amdgcn_mfma_f32_16x16x32_f16(bk0, aq0, s4, 0, 0, 0);
    s4 = __builtin_amdgcn_mfma_f32_16x16x32_f16(bk1, aq1, s4, 0, 0, 0);
    float e0 = exp2f(fmaf(s4[0], 0.18033688f, -11.5415603f));   // exp(s/8 - 8)
    float e1 = exp2f(fmaf(s4[1], 0.18033688f, -11.5415603f));
    float e2 = exp2f(fmaf(s4[2], 0.18033688f, -11.5415603f));
    float e3 = exp2f(fmaf(s4[3], 0.18033688f, -11.5415603f));
    S1 += e0 + e1 + e2 + e3;
    S2 += e0 * e0 + e1 * e1 + e2 * e2 + e3 * e3;
    h2f p0; p0[0] = (_Float16)e0; p0[1] = (_Float16)e1;
    h2f p1; p1[0] = (_Float16)e2; p1[1] = (_Float16)e3;
    kv[2 * i]     = __builtin_bit_cast(uint32_t, p0);
    kv[2 * i + 1] = __builtin_bit_cast(uint32_t, p1);
  }
  // reduce across the 4 quads (same score row l15)
  S1 += __shfl_xor(S1, 16); S1 += __shfl_xor(S1, 32);
  S2 += __shfl_xor(S2, 16); S2 += __shfl_xor(S2, 32);
  if (l < 16) {
    sums[(w * 16 + l15) * 2]     = S1;
    sums[(w * 16 + l15) * 2 + 1] = S2;
  }
  __syncthreads();   // B1
  float Z1 = 0.f, S2t = 0.f;
  #pragma unroll
  for (int ww = 0; ww < 4; ww++) {
    Z1  += sums[(ww * 16 + l15) * 2];
    S2t += sums[(ww * 16 + l15) * 2 + 1];
  }
  float invZ1 = 1.0f / Z1;
  float Z2 = 1025.0f + 0.5f * S2t * invZ1 * invZ1;
  float invZ2 = 1.0f / Z2;

  // c' = exp(w)/Z2 via packed-f16 Horner; write to LDS in phase-A layout
  _Float16 izh = (_Float16)invZ1;
  h2f izv; izv[0] = izh; izv[1] = izh;
  _Float16 z2h = (_Float16)invZ2;
  h2f z2v; z2v[0] = z2h; z2v[1] = z2h;
  h2f onev; onev[0] = (_Float16)1.f; onev[1] = (_Float16)1.f;
  h2f c2v;  c2v[0] = (_Float16)0.5f; c2v[1] = (_Float16)0.5f;
  h2f c6v;  c6v[0] = (_Float16)(1.f/6.f); c6v[1] = (_Float16)(1.f/6.f);
  #pragma unroll
  for (int i = 0; i < 16; i++) {
    int t0 = ((i << 2) | w) << 4;
    uint2 ov;
    #pragma unroll
    for (int hwd = 0; hwd < 2; hwd++) {
      h2f e = __builtin_bit_cast(h2f, kv[2 * i + hwd]);
      h2f wv = e * izv;
      h2f p = wv * c6v + c2v;
      h2f qq = wv * p + onev;
      h2f cm1 = wv * qq;
      h2f cp = cm1 * z2v + z2v;
      (&ov.x)[hwd] = __builtin_bit_cast(uint32_t, cp);
    }
    *(uint2*)(scb + l15 * RSTRIDE + t0 + quad * 4) = ov;
  }
  __syncthreads();   // B2

  // ---- phase E: o = c' @ V, V DMA-staged 4-deep (1 KB slots, per-wave private)
  int n0 = w << 4;
  const u16* crow = scb + l15 * RSTRIDE;
  const u16* vsrc = vb + (size_t)(n0 + lr) * S_ + lc * 8;
  f32x4 oacc = {};
  gl_lds16(vsrc,      &scb[ws + l * 8]);
  gl_lds16(vsrc + 32, &scb[ws + 512 + l * 8]);
  gl_lds16(vsrc + 64, &scb[ws + 1024 + l * 8]);
  #pragma unroll
  for (int kt = 0; kt < 32; kt++) {
    if (kt + 3 < 32)
      gl_lds16(vsrc + (kt + 3) * 32, &scb[ws + ((kt + 3) & 3) * 512 + l * 8]);
    if (kt < 29) { WAITVM(3); } else if (kt == 29) { WAITVM(2); }
    else if (kt == 30) { WAITVM(1); } else { WAITVM(0); }
    h8 ca = *(const h8*)(crow + kt * 32 + quad * 8);
    h8 vv = *(const h8*)&scb[ws + (kt & 3) * 512 + l15 * 32 + quad * 8];
    oacc = __builtin_amdgcn_mfma_f32_16x16x32_f16(ca, vv, oacc, 0, 0, 0);
  }
  int b = bh >> 3, hh = bh & 7;
  #pragma unroll
  for (int r = 0; r < 4; r++) {
    int rr = quad * 4 + r;
    attn[((size_t)b * S_ + r0 + rr) * D_ + hh * DH_ + n0 + l15] = f2bf(oacc[r]);
  }
}

// ---------------- RMS norm over D per row: fp32 in, bf16 out ----------------
__global__ __launch_bounds__(128) void rms_kernel(const float* __restrict__ in,
                                                  const float* __restrict__ w,
                                                  u16* __restrict__ out) {
  int row = blockIdx.x;
  int tid = threadIdx.x;
  const float* r = in + (size_t)row * D_;
  float v0 = r[tid], v1 = r[tid + 128], v2 = r[tid + 256], v3 = r[tid + 384];
  float s = v0 * v0 + v1 * v1 + v2 * v2 + v3 * v3;
  #pragma unroll
  for (int d = 1; d < 64; d <<= 1) s += __shfl_xor(s, d);
  __shared__ float red[2];
  if ((tid & 63) == 0) red[tid >> 6] = s;
  __syncthreads();
  s = red[0] + red[1];
  float rs = rsqrtf(s * (1.0f / 512.0f) + 1e-6f);
  out[(size_t)row * D_ + tid      ] = f2bf(v0 * rs * w[tid      ]);
  out[(size_t)row * D_ + tid + 128] = f2bf(v1 * rs * w[tid + 128]);
  out[(size_t)row * D_ + tid + 256] = f2bf(v2 * rs * w[tid + 256]);
  out[(size_t)row * D_ + tid + 384] = f2bf(v3 * rs * w[tid + 384]);
}

// ---------------- instance norm: stage-2 (partials fused into FFN-down) + apply ----------------
__global__ __launch_bounds__(256) void inorm_stats2(const float* __restrict__ part,
                                                    float* __restrict__ stats) {
  int idx = blockIdx.x * 256 + threadIdx.x;   // (b*512+d), 2048 total
  float s1 = 0.f, s2 = 0.f;
  #pragma unroll
  for (int i = 0; i < 8; i++) {
    float2 p = *(const float2*)&part[((size_t)idx * 8 + i) * 2];
    s1 += p.x; s2 += p.y;
  }
  float m = s1 * (1.f / 1024.f);
  float var = s2 * (1.f / 1024.f) - m * m;
  stats[idx * 2]     = m;
  stats[idx * 2 + 1] = rsqrtf(var + 1e-5f);
}

__global__ __launch_bounds__(256) void inorm_apply(const float* __restrict__ y,
                                                   const float* __restrict__ stats,
                                                   const float* __restrict__ w,
                                                   const float* __restrict__ bias,
                                                   float* __restrict__ out) {
  int row = blockIdx.x;
  int b = row >> 10;
  int tid = threadIdx.x;
  #pragma unroll
  for (int i = 0; i < 2; i++) {
    int d = tid + i * 256;
    float m  = stats[((size_t)b * D_ + d) * 2];
    float rs = stats[((size_t)b * D_ + d) * 2 + 1];
    float v = y[(size_t)row * D_ + d];
    out[(size_t)row * D_ + d] = (v - m) * rs * w[d] + bias[d];
  }
}

// ---------------- launch ----------------
extern "C" void kernel_launch(void* const* d_in, const int* in_sizes, int n_in,
                              void* d_out, int out_size, void* d_ws, size_t ws_size,
                              hipStream_t stream) {
  const float* x    = (const float*)d_in[0];
  const float* Wq   = (const float*)d_in[1];
  const float* bq   = (const float*)d_in[2];
  const float* Wkv  = (const float*)d_in[3];
  const float* bkv  = (const float*)d_in[4];
  const float* Wo   = (const float*)d_in[5];
  const float* bo   = (const float*)d_in[6];
  const float* rmsw = (const float*)d_in[7];
  const float* l1   = (const float*)d_in[8];
  const float* l2   = (const float*)d_in[9];
  const float* l3   = (const float*)d_in[10];
  const float* inw  = (const float*)d_in[11];
  const float* inb  = (const float*)d_in[12];
  float* out = (float*)d_out;

  char* ws = (char*)d_ws;
  size_t off = 0;
  auto alloc = [&](size_t n) { char* p = ws + off; off += (n + 255) & ~(size_t)255; return p; };
  u16*  xb   = (u16*) alloc((size_t)M_ * D_ * 2);
  u16*  Wt1  = (u16*) alloc((size_t)1536 * 512 * 2);
  u16*  Wot  = (u16*) alloc((size_t)512 * 512 * 2);
  u16*  W12t = (u16*) alloc((size_t)3072 * 512 * 2);   // interleaved l1/l2
  u16*  l3t  = (u16*) alloc((size_t)512 * 1536 * 2);
  u16*  qb   = (u16*) alloc((size_t)M_ * D_ * 2);      // f16 [B,H,S,DH]
  u16*  kb   = (u16*) alloc((size_t)M_ * D_ * 2);      // f16 [B,H,S,DH]
  u16*  vtb  = (u16*) alloc((size_t)M_ * D_ * 2);      // f16 [B,H,DH,S]
  u16*  attn = (u16*) alloc((size_t)M_ * D_ * 2);      // bf16 [B,S,D]
  float* tmpF = (float*)alloc((size_t)M_ * D_ * 4);
  u16*  hhat = (u16*) alloc((size_t)M_ * D_ * 2);
  u16*  g    = (u16*) alloc((size_t)M_ * INNER_ * 2);
  float* part  = (float*)alloc((size_t)B_ * D_ * 8 * 2 * 4);
  float* stats = (float*)alloc((size_t)B_ * D_ * 2 * 4);

  transpose_all<<<832, 256, 0, stream>>>(Wq, Wkv, Wo, l1, l2, l3, Wt1, Wot, W12t, l3t);
  f2b_kernel<<<2048, 256, 0, stream>>>(x, xb);

  gemm_bt<1><<<dim3(12, 32), 256, 0, stream>>>(xb, Wt1, M_, 1536, 512,
      bq, bkv, nullptr, qb, kb, vtb);

  attn_kernel<<<2048, 256, 0, stream>>>(qb, kb, vtb, attn);

  gemm_n64<2><<<dim3(8, 32), 256, 0, stream>>>(attn, Wot, M_, 512, 512,
      bo, x, nullptr, tmpF, nullptr);

  rms_kernel<<<4096, 128, 0, stream>>>(tmpF, rmsw, hhat);

  // FFN up + silu fused: writes g [M, 1536] directly
  gemm_bt<3><<<dim3(24, 32), 256, 0, stream>>>(hhat, W12t, M_, 3072, 512,
      nullptr, nullptr, g, nullptr, nullptr, nullptr);

  // FFN down + residual + fused instance-norm partial sums
  gemm_n64<4><<<dim3(8, 32), 256, 0, stream>>>(g, l3t, M_, 512, 1536,
      nullptr, nullptr, hhat, tmpF, part);

  inorm_stats2<<<8, 256, 0, stream>>>(part, stats);
  inorm_apply<<<4096, 256, 0, stream>>>(tmpF, stats, inw, inb, out);
}

// Round 12
// 224.712 us; speedup vs baseline: 1.2014x; 1.0136x over previous
//
#include <hip/hip_runtime.h>
#include <stdint.h>

#define B_ 4
#define S_ 1024
#define D_ 512
#define H_ 8
#define DH_ 64
#define INNER_ 1536
#define M_ (B_*S_)   // 4096

typedef unsigned short u16;
typedef __attribute__((ext_vector_type(8))) short sh8;      // 8 bf16
typedef __attribute__((ext_vector_type(8))) _Float16 h8;    // 8 f16
typedef __attribute__((ext_vector_type(4))) _Float16 h4;    // 4 f16
typedef __attribute__((ext_vector_type(2))) _Float16 h2f;   // 2 f16
typedef __attribute__((ext_vector_type(4))) float f32x4;

typedef __attribute__((address_space(1))) const void cgv;
typedef __attribute__((address_space(3))) void lv;
__device__ __forceinline__ void gl_lds16(const void* g, void* l) {
  __builtin_amdgcn_global_load_lds((cgv*)g, (lv*)l, 16, 0, 0);
}
// wait until <=N vm ops outstanding; ignore lgkm(15)/exp(7)
#define WAITVM(N) __builtin_amdgcn_s_waitcnt(0x0F70 | (N))

__device__ __forceinline__ float bf2f(u16 u) {
  union { unsigned int i; float f; } v; v.i = ((unsigned int)u) << 16; return v.f;
}
__device__ __forceinline__ u16 f2bf(float f) {
  union { float f; unsigned int i; } v; v.f = f;
  unsigned int u = v.i;
  return (u16)((u + 0x7FFFu + ((u >> 16) & 1u)) >> 16);
}
__device__ __forceinline__ u16 f2h(float f) {
  _Float16 h = (_Float16)f;
  return *(u16*)&h;
}

// ---------------- transposes + x->bf16 in ONE launch ----------------
// l1/l2 interleaved into W12t: l1 col j -> row 2j, l2 col j -> row 2j+1.
// blocks 832..2879 convert x (fp32 -> bf16), 4 elems/thread.
__global__ __launch_bounds__(256) void prep_all(
    const float* __restrict__ Wq, const float* __restrict__ Wkv,
    const float* __restrict__ Wo, const float* __restrict__ l1,
    const float* __restrict__ l2, const float* __restrict__ l3,
    const float* __restrict__ x,
    u16* __restrict__ Wt1, u16* __restrict__ Wot,
    u16* __restrict__ W12t, u16* __restrict__ l3t,
    u16* __restrict__ xb)
{
  int i = blockIdx.x;
  if (i >= 832) {
    int e = ((i - 832) * 256 + threadIdx.x) * 4;
    float4 v = *(const float4*)(x + e);
    uint2 o;
    o.x = (unsigned int)f2bf(v.x) | ((unsigned int)f2bf(v.y) << 16);
    o.y = (unsigned int)f2bf(v.z) | ((unsigned int)f2bf(v.w) << 16);
    *(uint2*)(xb + e) = o;
    return;
  }
  const float* in; u16* outp; int K, N, bx, by, rs = 1, ra = 0;
  if (i < 64)       { in = Wq;  outp = Wt1;              K = 512;  N = 512;           bx = i & 7;  by = i >> 3; }
  else if (i < 192) { in = Wkv; outp = Wt1 + 512 * 512;  K = 512;  N = 1024; i -= 64; bx = i & 15; by = i >> 4; }
  else if (i < 256) { in = Wo;  outp = Wot;              K = 512;  N = 512;  i -= 192; bx = i & 7;  by = i >> 3; }
  else if (i < 448) { in = l1;  outp = W12t;             K = 512;  N = 1536; i -= 256; bx = i % 24; by = i / 24; rs = 2; ra = 0; }
  else if (i < 640) { in = l2;  outp = W12t;             K = 512;  N = 1536; i -= 448; bx = i % 24; by = i / 24; rs = 2; ra = 1; }
  else              { in = l3;  outp = l3t;              K = 1536; N = 512;  i -= 640; bx = i & 7;  by = i >> 3; }

  __shared__ u16 tile[64][65];
  int tx = threadIdx.x & 63, ty = threadIdx.x >> 6;
  int n0 = bx * 64, k0 = by * 64;
  #pragma unroll
  for (int t = 0; t < 16; t++) {
    int k = ty + t * 4;
    tile[k][tx] = f2bf(in[(size_t)(k0 + k) * N + n0 + tx]);
  }
  __syncthreads();
  #pragma unroll
  for (int t = 0; t < 16; t++) {
    int n = ty + t * 4;
    outp[(size_t)((n0 + n) * rs + ra) * K + k0 + tx] = tile[tx][n];
  }
}

// ---------------- 128x128 GEMM, glds staging, BK=64 (2 sub-tiles/barrier) ----------------
// EPI 1: qkv scatter (+biases), q/k/v stored f16
// EPI 3: silu-fused FFN-up: interleaved l1/l2 cols; writes g[M, N/2] bf16
template<int EPI>
__global__ __launch_bounds__(256) void gemm_bt(
    const u16* __restrict__ A, const u16* __restrict__ Bt,
    int M, int N, int K,
    const float* __restrict__ bias0, const float* __restrict__ bias1,
    u16* __restrict__ outU,
    u16* __restrict__ qo, u16* __restrict__ ko_, u16* __restrict__ vto)
{
  __shared__ u16 As[2 * 128 * 32];
  __shared__ u16 Bs[2 * 128 * 32];
  int tid = threadIdx.x;
  int gx = blockIdx.x, gy = blockIdx.y;
  int l = tid & 63, w = tid >> 6;
  int l15 = l & 15, quad = l >> 4;
  int wm = (w >> 1) * 64, wn = (w & 1) * 64;
  f32x4 acc[4][4] = {};

  const u16* Ag = A  + (size_t)(gy * 128 + (tid >> 2)) * K + (tid & 3) * 8;
  const u16* Bg = Bt + (size_t)(gx * 128 + (tid >> 2)) * K + (tid & 3) * 8;

  for (int ko = 0; ko < K; ko += 64) {
    __syncthreads();
    gl_lds16(Ag + ko,                       &As[tid * 8]);
    gl_lds16(Ag + (size_t)64 * K + ko,      &As[2048 + tid * 8]);
    gl_lds16(Ag + ko + 32,                  &As[4096 + tid * 8]);
    gl_lds16(Ag + (size_t)64 * K + ko + 32, &As[6144 + tid * 8]);
    gl_lds16(Bg + ko,                       &Bs[tid * 8]);
    gl_lds16(Bg + (size_t)64 * K + ko,      &Bs[2048 + tid * 8]);
    gl_lds16(Bg + ko + 32,                  &Bs[4096 + tid * 8]);
    gl_lds16(Bg + (size_t)64 * K + ko + 32, &Bs[6144 + tid * 8]);
    __syncthreads();
    #pragma unroll
    for (int sub = 0; sub < 2; sub++) {
      int base = sub * 4096;
      sh8 af[4], bfr[4];
      #pragma unroll
      for (int mi = 0; mi < 4; mi++)
        af[mi] = *(const sh8*)&As[base + (wm + mi * 16 + l15) * 32 + quad * 8];
      #pragma unroll
      for (int ni = 0; ni < 4; ni++)
        bfr[ni] = *(const sh8*)&Bs[base + (wn + ni * 16 + l15) * 32 + quad * 8];
      #pragma unroll
      for (int mi = 0; mi < 4; mi++)
        #pragma unroll
        for (int ni = 0; ni < 4; ni++)
          acc[mi][ni] = __builtin_amdgcn_mfma_f32_16x16x32_bf16(af[mi], bfr[ni], acc[mi][ni], 0, 0, 0);
    }
  }

  #pragma unroll
  for (int mi = 0; mi < 4; mi++) {
    #pragma unroll
    for (int ni = 0; ni < 4; ni++) {
      #pragma unroll
      for (int r = 0; r < 4; r++) {
        int grow = gy * 128 + wm + mi * 16 + quad * 4 + r;
        int gcol = gx * 128 + wn + ni * 16 + l15;
        float v = acc[mi][ni][r];
        if (EPI == 1) {
          int b = grow >> 10, s = grow & 1023;
          if (gcol < 512) {
            int h = gcol >> 6, dh = gcol & 63;
            qo[(((size_t)b * H_ + h) * S_ + s) * DH_ + dh] = f2h(v + bias0[gcol]);
          } else {
            int n2 = gcol - 512;
            int two = n2 >> 9, h = (n2 >> 6) & 7, dh = n2 & 63;
            float vv = v + bias1[n2];
            if (two == 0) ko_[(((size_t)b * H_ + h) * S_ + s) * DH_ + dh] = f2h(vv);
            else          vto[(((size_t)b * H_ + h) * DH_ + dh) * S_ + s] = f2h(vv);
          }
        } else {
          float vp = __shfl_xor(v, 1);
          if ((l15 & 1) == 0) {
            float a = v, b = vp;
            float gv = a / (1.f + __expf(-a)) * b;
            outU[(size_t)grow * (N >> 1) + (gcol >> 1)] = f2bf(gv);
          }
        }
      }
    }
  }
}

// ---------------- 128x64 GEMM for small-N layers (256 blocks, 8 MFMA/iter) ----------------
// EPI 2: +bias0 +auxF(fp32) -> outF
// EPI 4: +auxH(bf16) -> outF, fused per-column partial sums -> part (for instance norm)
template<int EPI>
__global__ __launch_bounds__(256) void gemm_n64(
    const u16* __restrict__ A, const u16* __restrict__ Bt,
    int M, int N, int K,
    const float* __restrict__ bias0, const float* __restrict__ auxF,
    const u16* __restrict__ auxH, float* __restrict__ outF,
    float* __restrict__ part)
{
  __shared__ u16 As[128 * 32];
  __shared__ u16 Bs[64 * 32];
  __shared__ float ss1[4][2][16], ss2[4][2][16];
  int tid = threadIdx.x;
  int gx = blockIdx.x, gy = blockIdx.y;
  int l = tid & 63, w = tid >> 6;
  int l15 = l & 15, quad = l >> 4;
  int wm = (w >> 1) * 64, wn = (w & 1) * 32;
  f32x4 acc[4][2] = {};

  const u16* Ag = A  + (size_t)(gy * 128 + (tid >> 2)) * K + (tid & 3) * 8;
  const u16* Bg = Bt + (size_t)(gx * 64  + (tid >> 2)) * K + (tid & 3) * 8;

  for (int ko = 0; ko < K; ko += 32) {
    __syncthreads();
    gl_lds16(Ag + ko,                  &As[tid * 8]);
    gl_lds16(Ag + (size_t)64 * K + ko, &As[2048 + tid * 8]);
    gl_lds16(Bg + ko,                  &Bs[tid * 8]);
    __syncthreads();
    sh8 af[4], bfr[2];
    #pragma unroll
    for (int mi = 0; mi < 4; mi++)
      af[mi] = *(const sh8*)&As[(wm + mi * 16 + l15) * 32 + quad * 8];
    #pragma unroll
    for (int ni = 0; ni < 2; ni++)
      bfr[ni] = *(const sh8*)&Bs[(wn + ni * 16 + l15) * 32 + quad * 8];
    #pragma unroll
    for (int mi = 0; mi < 4; mi++)
      #pragma unroll
      for (int ni = 0; ni < 2; ni++)
        acc[mi][ni] = __builtin_amdgcn_mfma_f32_16x16x32_bf16(af[mi], bfr[ni], acc[mi][ni], 0, 0, 0);
  }

  float cs1[2] = {0.f, 0.f}, cs2[2] = {0.f, 0.f};
  #pragma unroll
  for (int mi = 0; mi < 4; mi++) {
    #pragma unroll
    for (int ni = 0; ni < 2; ni++) {
      #pragma unroll
      for (int r = 0; r < 4; r++) {
        int grow = gy * 128 + wm + mi * 16 + quad * 4 + r;
        int gcol = gx * 64 + wn + ni * 16 + l15;
        float v = acc[mi][ni][r];
        if (EPI == 2) v += bias0[gcol] + auxF[(size_t)grow * N + gcol];
        else          v += bf2f(auxH[(size_t)grow * N + gcol]);
        outF[(size_t)grow * N + gcol] = v;
        if (EPI == 4) { cs1[ni] += v; cs2[ni] += v * v; }
      }
    }
  }
  if (EPI == 4) {
    #pragma unroll
    for (int ni = 0; ni < 2; ni++) {
      cs1[ni] += __shfl_xor(cs1[ni], 16); cs1[ni] += __shfl_xor(cs1[ni], 32);
      cs2[ni] += __shfl_xor(cs2[ni], 16); cs2[ni] += __shfl_xor(cs2[ni], 32);
    }
    if (l < 16) {
      ss1[w][0][l15] = cs1[0]; ss1[w][1][l15] = cs1[1];
      ss2[w][0][l15] = cs2[0]; ss2[w][1][l15] = cs2[1];
    }
    __syncthreads();
    if (tid < 64) {
      int wsel = (tid >> 5) & 1, ni = (tid >> 4) & 1, cl = tid & 15;
      float s1 = ss1[wsel][ni][cl] + ss1[wsel + 2][ni][cl];
      float s2 = ss2[wsel][ni][cl] + ss2[wsel + 2][ni][cl];
      int col = gx * 64 + wsel * 32 + ni * 16 + cl;
      int b = gy >> 3, seg = gy & 7;
      float2 p; p.x = s1; p.y = s2;
      *(float2*)&part[((size_t)(b * 512 + col) * 8 + seg) * 2] = p;
    }
  }
}

// ---------------- sparse attention v8: DMA K/V rings + register-sum softmax ----------------
// Z1 = sum e', Z2 = 1025 + S2/(2 Z1^2) (maskless Taylor softmax2, validated r8/r10).
#define RSTRIDE 1032                 // halves; c' row stride (2064 B)
#define STAGE_H (16 * RSTRIDE)       // staging region offset, halves
__global__ __launch_bounds__(256, 3) void attn_kernel(
    const u16* __restrict__ q, const u16* __restrict__ kk,
    const u16* __restrict__ vt, u16* __restrict__ attn)
{
  // c' 33,024B + staging 16,384B + sums 512B = 49,920B -> 3 blocks/CU
  __shared__ u16 scb[16 * RSTRIDE + 4 * 2048 + 256];
  float* sums = (float*)(scb + 16 * RSTRIDE + 4 * 2048);

  int tid = threadIdx.x;
  int l = tid & 63, w = tid >> 6;
  int l15 = l & 15, quad = l >> 4;
  int blk = blockIdx.x;
  // XCD-aware swizzle: 4 bh per XCD
  int xcd = blk & 7, li = blk >> 3;
  int bh = xcd * 4 + (li & 3);
  int r0 = (li >> 2) << 4;

  const u16* qb = q  + ((size_t)bh * S_ + r0) * DH_;
  const u16* kb = kk + (size_t)bh * S_ * DH_;
  const u16* vb = vt + (size_t)bh * DH_ * S_;

  int ws = STAGE_H + w * 2048;     // per-wave private staging base (halves)
  int lr = l >> 2, lc = l & 3;

  h8 aq0 = *(const h8*)(qb + l15 * DH_ + quad * 8);
  h8 aq1 = *(const h8*)(qb + l15 * DH_ + 32 + quad * 8);

  // ---- phase A: K DMA-staged 2-deep; e' kept in registers; S1,S2 accumulated
  uint32_t kv[32];
  float S1 = 0.f, S2 = 0.f;
  #pragma unroll
  for (int i = 0; i < 16; i++) {
    if (i == 0) {
      const u16* src = kb + (size_t)((w << 4) + lr) * DH_ + lc * 8;
      gl_lds16(src,      &scb[ws + l * 8]);
      gl_lds16(src + 32, &scb[ws + 512 + l * 8]);
    }
    if (i + 1 < 16) {
      int t0n = (((i + 1) << 2) | w) << 4;
      const u16* src = kb + (size_t)(t0n + lr) * DH_ + lc * 8;
      int sb = ws + ((i + 1) & 1) * 1024;
      gl_lds16(src,      &scb[sb + l * 8]);
      gl_lds16(src + 32, &scb[sb + 512 + l * 8]);
    }
    if (i + 1 < 16) { WAITVM(2); } else { WAITVM(0); }
    int sb = ws + (i & 1) * 1024;
    h8 bk0 = *(const h8*)&scb[sb + l15 * 32 + quad * 8];
    h8 bk1 = *(const h8*)&scb[sb + 512 + l15 * 32 + quad * 8];
    f32x4 s4 = {};
    s4 = __builtin_amdgcn_mfma_f32_16x16x32_f16(bk0, aq0, s4, 0, 0, 0);
    s4 = __builtin_amdgcn_mfma_f32_16x16x32_f16(bk1, aq1, s4, 0, 0, 0);
    float e0 = exp2f(fmaf(s4[0], 0.18033688f, -11.5415603f));   // exp(s/8 - 8)
    float e1 = exp2f(fmaf(s4[1], 0.18033688f, -11.5415603f));
    float e2 = exp2f(fmaf(s4[2], 0.18033688f, -11.5415603f));
    float e3 = exp2f(fmaf(s4[3], 0.18033688f, -11.5415603f));
    S1 += e0 + e1 + e2 + e3;
    S2 += e0 * e0 + e1 * e1 + e2 * e2 + e3 * e3;
    h2f p0; p0[0] = (_Float16)e0; p0[1] = (_Float16)e1;
    h2f p1; p1[0] = (_Float16)e2; p1[1] = (_Float16)e3;
    kv[2 * i]     = __builtin_bit_cast(uint32_t, p0);
    kv[2 * i + 1] = __builtin_bit_cast(uint32_t, p1);
  }
  // reduce across the 4 quads (same score row l15)
  S1 += __shfl_xor(S1, 16); S1 += __shfl_xor(S1, 32);
  S2 += __shfl_xor(S2, 16); S2 += __shfl_xor(S2, 32);
  if (l < 16) {
    sums[(w * 16 + l15) * 2]     = S1;
    sums[(w * 16 + l15) * 2 + 1] = S2;
  }
  __syncthreads();   // B1
  float Z1 = 0.f, S2t = 0.f;
  #pragma unroll
  for (int ww = 0; ww < 4; ww++) {
    Z1  += sums[(ww * 16 + l15) * 2];
    S2t += sums[(ww * 16 + l15) * 2 + 1];
  }
  float invZ1 = 1.0f / Z1;
  float Z2 = 1025.0f + 0.5f * S2t * invZ1 * invZ1;
  float invZ2 = 1.0f / Z2;

  // c' = exp(w)/Z2 via packed-f16 Horner; write to LDS in phase-A layout
  _Float16 izh = (_Float16)invZ1;
  h2f izv; izv[0] = izh; izv[1] = izh;
  _Float16 z2h = (_Float16)invZ2;
  h2f z2v; z2v[0] = z2h; z2v[1] = z2h;
  h2f onev; onev[0] = (_Float16)1.f; onev[1] = (_Float16)1.f;
  h2f c2v;  c2v[0] = (_Float16)0.5f; c2v[1] = (_Float16)0.5f;
  h2f c6v;  c6v[0] = (_Float16)(1.f/6.f); c6v[1] = (_Float16)(1.f/6.f);
  #pragma unroll
  for (int i = 0; i < 16; i++) {
    int t0 = ((i << 2) | w) << 4;
    uint2 ov;
    #pragma unroll
    for (int hwd = 0; hwd < 2; hwd++) {
      h2f e = __builtin_bit_cast(h2f, kv[2 * i + hwd]);
      h2f wv = e * izv;
      h2f p = wv * c6v + c2v;
      h2f qq = wv * p + onev;
      h2f cm1 = wv * qq;
      h2f cp = cm1 * z2v + z2v;
      (&ov.x)[hwd] = __builtin_bit_cast(uint32_t, cp);
    }
    *(uint2*)(scb + l15 * RSTRIDE + t0 + quad * 4) = ov;
  }
  __syncthreads();   // B2

  // ---- phase E: o = c' @ V, V DMA-staged 4-deep (1 KB slots, per-wave private)
  int n0 = w << 4;
  const u16* crow = scb + l15 * RSTRIDE;
  const u16* vsrc = vb + (size_t)(n0 + lr) * S_ + lc * 8;
  f32x4 oacc = {};
  gl_lds16(vsrc,      &scb[ws + l * 8]);
  gl_lds16(vsrc + 32, &scb[ws + 512 + l * 8]);
  gl_lds16(vsrc + 64, &scb[ws + 1024 + l * 8]);
  #pragma unroll
  for (int kt = 0; kt < 32; kt++) {
    if (kt + 3 < 32)
      gl_lds16(vsrc + (kt + 3) * 32, &scb[ws + ((kt + 3) & 3) * 512 + l * 8]);
    if (kt < 29) { WAITVM(3); } else if (kt == 29) { WAITVM(2); }
    else if (kt == 30) { WAITVM(1); } else { WAITVM(0); }
    h8 ca = *(const h8*)(crow + kt * 32 + quad * 8);
    h8 vv = *(const h8*)&scb[ws + (kt & 3) * 512 + l15 * 32 + quad * 8];
    oacc = __builtin_amdgcn_mfma_f32_16x16x32_f16(ca, vv, oacc, 0, 0, 0);
  }
  int b = bh >> 3, hh = bh & 7;
  #pragma unroll
  for (int r = 0; r < 4; r++) {
    int rr = quad * 4 + r;
    attn[((size_t)b * S_ + r0 + rr) * D_ + hh * DH_ + n0 + l15] = f2bf(oacc[r]);
  }
}

// ---------------- RMS norm over D per row: fp32 in, bf16 out ----------------
__global__ __launch_bounds__(128) void rms_kernel(const float* __restrict__ in,
                                                  const float* __restrict__ w,
                                                  u16* __restrict__ out) {
  int row = blockIdx.x;
  int tid = threadIdx.x;
  const float* r = in + (size_t)row * D_;
  float v0 = r[tid], v1 = r[tid + 128], v2 = r[tid + 256], v3 = r[tid + 384];
  float s = v0 * v0 + v1 * v1 + v2 * v2 + v3 * v3;
  #pragma unroll
  for (int d = 1; d < 64; d <<= 1) s += __shfl_xor(s, d);
  __shared__ float red[2];
  if ((tid & 63) == 0) red[tid >> 6] = s;
  __syncthreads();
  s = red[0] + red[1];
  float rs = rsqrtf(s * (1.0f / 512.0f) + 1e-6f);
  out[(size_t)row * D_ + tid      ] = f2bf(v0 * rs * w[tid      ]);
  out[(size_t)row * D_ + tid + 128] = f2bf(v1 * rs * w[tid + 128]);
  out[(size_t)row * D_ + tid + 256] = f2bf(v2 * rs * w[tid + 256]);
  out[(size_t)row * D_ + tid + 384] = f2bf(v3 * rs * w[tid + 384]);
}

// ---------------- instance norm: stage-2 (partials fused into FFN-down) + apply ----------------
__global__ __launch_bounds__(256) void inorm_stats2(const float* __restrict__ part,
                                                    float* __restrict__ stats) {
  int idx = blockIdx.x * 256 + threadIdx.x;   // (b*512+d), 2048 total
  float s1 = 0.f, s2 = 0.f;
  #pragma unroll
  for (int i = 0; i < 8; i++) {
    float2 p = *(const float2*)&part[((size_t)idx * 8 + i) * 2];
    s1 += p.x; s2 += p.y;
  }
  float m = s1 * (1.f / 1024.f);
  float var = s2 * (1.f / 1024.f) - m * m;
  stats[idx * 2]     = m;
  stats[idx * 2 + 1] = rsqrtf(var + 1e-5f);
}

__global__ __launch_bounds__(256) void inorm_apply(const float* __restrict__ y,
                                                   const float* __restrict__ stats,
                                                   const float* __restrict__ w,
                                                   const float* __restrict__ bias,
                                                   float* __restrict__ out) {
  int row = blockIdx.x;
  int b = row >> 10;
  int tid = threadIdx.x;
  #pragma unroll
  for (int i = 0; i < 2; i++) {
    int d = tid + i * 256;
    float m  = stats[((size_t)b * D_ + d) * 2];
    float rs = stats[((size_t)b * D_ + d) * 2 + 1];
    float v = y[(size_t)row * D_ + d];
    out[(size_t)row * D_ + d] = (v - m) * rs * w[d] + bias[d];
  }
}

// ---------------- launch ----------------
extern "C" void kernel_launch(void* const* d_in, const int* in_sizes, int n_in,
                              void* d_out, int out_size, void* d_ws, size_t ws_size,
                              hipStream_t stream) {
  const float* x    = (const float*)d_in[0];
  const float* Wq   = (const float*)d_in[1];
  const float* bq   = (const float*)d_in[2];
  const float* Wkv  = (const float*)d_in[3];
  const float* bkv  = (const float*)d_in[4];
  const float* Wo   = (const float*)d_in[5];
  const float* bo   = (const float*)d_in[6];
  const float* rmsw = (const float*)d_in[7];
  const float* l1   = (const float*)d_in[8];
  const float* l2   = (const float*)d_in[9];
  const float* l3   = (const float*)d_in[10];
  const float* inw  = (const float*)d_in[11];
  const float* inb  = (const float*)d_in[12];
  float* out = (float*)d_out;

  char* ws = (char*)d_ws;
  size_t off = 0;
  auto alloc = [&](size_t n) { char* p = ws + off; off += (n + 255) & ~(size_t)255; return p; };
  u16*  xb   = (u16*) alloc((size_t)M_ * D_ * 2);
  u16*  Wt1  = (u16*) alloc((size_t)1536 * 512 * 2);
  u16*  Wot  = (u16*) alloc((size_t)512 * 512 * 2);
  u16*  W12t = (u16*) alloc((size_t)3072 * 512 * 2);   // interleaved l1/l2
  u16*  l3t  = (u16*) alloc((size_t)512 * 1536 * 2);
  u16*  qb   = (u16*) alloc((size_t)M_ * D_ * 2);      // f16 [B,H,S,DH]
  u16*  kb   = (u16*) alloc((size_t)M_ * D_ * 2);      // f16 [B,H,S,DH]
  u16*  vtb  = (u16*) alloc((size_t)M_ * D_ * 2);      // f16 [B,H,DH,S]
  u16*  attn = (u16*) alloc((size_t)M_ * D_ * 2);      // bf16 [B,S,D]
  float* tmpF = (float*)alloc((size_t)M_ * D_ * 4);
  u16*  hhat = (u16*) alloc((size_t)M_ * D_ * 2);
  u16*  g    = (u16*) alloc((size_t)M_ * INNER_ * 2);
  float* part  = (float*)alloc((size_t)B_ * D_ * 8 * 2 * 4);
  float* stats = (float*)alloc((size_t)B_ * D_ * 2 * 4);

  prep_all<<<2880, 256, 0, stream>>>(Wq, Wkv, Wo, l1, l2, l3, x,
                                     Wt1, Wot, W12t, l3t, xb);

  gemm_bt<1><<<dim3(12, 32), 256, 0, stream>>>(xb, Wt1, M_, 1536, 512,
      bq, bkv, nullptr, qb, kb, vtb);

  attn_kernel<<<2048, 256, 0, stream>>>(qb, kb, vtb, attn);

  gemm_n64<2><<<dim3(8, 32), 256, 0, stream>>>(attn, Wot, M_, 512, 512,
      bo, x, nullptr, tmpF, nullptr);

  rms_kernel<<<4096, 128, 0, stream>>>(tmpF, rmsw, hhat);

  // FFN up + silu fused: writes g [M, 1536] directly
  gemm_bt<3><<<dim3(24, 32), 256, 0, stream>>>(hhat, W12t, M_, 3072, 512,
      nullptr, nullptr, g, nullptr, nullptr, nullptr);

  // FFN down + residual + fused instance-norm partial sums
  gemm_n64<4><<<dim3(8, 32), 256, 0, stream>>>(g, l3t, M_, 512, 1536,
      nullptr, nullptr, hhat, tmpF, part);

  inorm_stats2<<<8, 256, 0, stream>>>(part, stats);
  inorm_apply<<<4096, 256, 0, stream>>>(tmpF, stats, inw, inb, out);
}

// Round 13
// 224.087 us; speedup vs baseline: 1.2047x; 1.0028x over previous
//
#include <hip/hip_runtime.h>
#include <stdint.h>

#define B_ 4
#define S_ 1024
#define D_ 512
#define H_ 8
#define DH_ 64
#define INNER_ 1536
#define M_ (B_*S_)   // 4096

typedef unsigned short u16;
typedef __attribute__((ext_vector_type(8))) short sh8;      // 8 bf16
typedef __attribute__((ext_vector_type(8))) _Float16 h8;    // 8 f16
typedef __attribute__((ext_vector_type(4))) _Float16 h4;    // 4 f16
typedef __attribute__((ext_vector_type(2))) _Float16 h2f;   // 2 f16
typedef __attribute__((ext_vector_type(4))) float f32x4;

typedef __attribute__((address_space(1))) const void cgv;
typedef __attribute__((address_space(3))) void lv;
__device__ __forceinline__ void gl_lds16(const void* g, void* l) {
  __builtin_amdgcn_global_load_lds((cgv*)g, (lv*)l, 16, 0, 0);
}
// wait until <=N vm ops outstanding; ignore lgkm(15)/exp(7)
#define WAITVM(N) __builtin_amdgcn_s_waitcnt(0x0F70 | (N))

__device__ __forceinline__ float bf2f(u16 u) {
  union { unsigned int i; float f; } v; v.i = ((unsigned int)u) << 16; return v.f;
}
__device__ __forceinline__ u16 f2bf(float f) {
  union { float f; unsigned int i; } v; v.f = f;
  unsigned int u = v.i;
  return (u16)((u + 0x7FFFu + ((u >> 16) & 1u)) >> 16);
}
__device__ __forceinline__ u16 f2h(float f) {
  _Float16 h = (_Float16)f;
  return *(u16*)&h;
}

// ---------------- transposes + x->bf16 in ONE launch ----------------
__global__ __launch_bounds__(256) void prep_all(
    const float* __restrict__ Wq, const float* __restrict__ Wkv,
    const float* __restrict__ Wo, const float* __restrict__ l1,
    const float* __restrict__ l2, const float* __restrict__ l3,
    const float* __restrict__ x,
    u16* __restrict__ Wt1, u16* __restrict__ Wot,
    u16* __restrict__ W12t, u16* __restrict__ l3t,
    u16* __restrict__ xb)
{
  int i = blockIdx.x;
  if (i >= 832) {
    int e = ((i - 832) * 256 + threadIdx.x) * 4;
    float4 v = *(const float4*)(x + e);
    uint2 o;
    o.x = (unsigned int)f2bf(v.x) | ((unsigned int)f2bf(v.y) << 16);
    o.y = (unsigned int)f2bf(v.z) | ((unsigned int)f2bf(v.w) << 16);
    *(uint2*)(xb + e) = o;
    return;
  }
  const float* in; u16* outp; int K, N, bx, by, rs = 1, ra = 0;
  if (i < 64)       { in = Wq;  outp = Wt1;              K = 512;  N = 512;           bx = i & 7;  by = i >> 3; }
  else if (i < 192) { in = Wkv; outp = Wt1 + 512 * 512;  K = 512;  N = 1024; i -= 64; bx = i & 15; by = i >> 4; }
  else if (i < 256) { in = Wo;  outp = Wot;              K = 512;  N = 512;  i -= 192; bx = i & 7;  by = i >> 3; }
  else if (i < 448) { in = l1;  outp = W12t;             K = 512;  N = 1536; i -= 256; bx = i % 24; by = i / 24; rs = 2; ra = 0; }
  else if (i < 640) { in = l2;  outp = W12t;             K = 512;  N = 1536; i -= 448; bx = i % 24; by = i / 24; rs = 2; ra = 1; }
  else              { in = l3;  outp = l3t;              K = 1536; N = 512;  i -= 640; bx = i & 7;  by = i >> 3; }

  __shared__ u16 tile[64][65];
  int tx = threadIdx.x & 63, ty = threadIdx.x >> 6;
  int n0 = bx * 64, k0 = by * 64;
  #pragma unroll
  for (int t = 0; t < 16; t++) {
    int k = ty + t * 4;
    tile[k][tx] = f2bf(in[(size_t)(k0 + k) * N + n0 + tx]);
  }
  __syncthreads();
  #pragma unroll
  for (int t = 0; t < 16; t++) {
    int n = ty + t * 4;
    outp[(size_t)((n0 + n) * rs + ra) * K + k0 + tx] = tile[tx][n];
  }
}

// ---------------- 128x128 GEMM, glds staging, BK=64 (2 sub-tiles/barrier) ----------------
// EPI 1: qkv scatter (+biases), q/k/v stored f16
// EPI 3: silu-fused FFN-up: interleaved l1/l2 cols; writes g[M, N/2] bf16
template<int EPI>
__global__ __launch_bounds__(256) void gemm_bt(
    const u16* __restrict__ A, const u16* __restrict__ Bt,
    int M, int N, int K,
    const float* __restrict__ bias0, const float* __restrict__ bias1,
    u16* __restrict__ outU,
    u16* __restrict__ qo, u16* __restrict__ ko_, u16* __restrict__ vto)
{
  __shared__ u16 As[2 * 128 * 32];
  __shared__ u16 Bs[2 * 128 * 32];
  int tid = threadIdx.x;
  int gx = blockIdx.x, gy = blockIdx.y;
  int l = tid & 63, w = tid >> 6;
  int l15 = l & 15, quad = l >> 4;
  int wm = (w >> 1) * 64, wn = (w & 1) * 64;
  f32x4 acc[4][4] = {};

  const u16* Ag = A  + (size_t)(gy * 128 + (tid >> 2)) * K + (tid & 3) * 8;
  const u16* Bg = Bt + (size_t)(gx * 128 + (tid >> 2)) * K + (tid & 3) * 8;

  for (int ko = 0; ko < K; ko += 64) {
    __syncthreads();
    gl_lds16(Ag + ko,                       &As[tid * 8]);
    gl_lds16(Ag + (size_t)64 * K + ko,      &As[2048 + tid * 8]);
    gl_lds16(Ag + ko + 32,                  &As[4096 + tid * 8]);
    gl_lds16(Ag + (size_t)64 * K + ko + 32, &As[6144 + tid * 8]);
    gl_lds16(Bg + ko,                       &Bs[tid * 8]);
    gl_lds16(Bg + (size_t)64 * K + ko,      &Bs[2048 + tid * 8]);
    gl_lds16(Bg + ko + 32,                  &Bs[4096 + tid * 8]);
    gl_lds16(Bg + (size_t)64 * K + ko + 32, &Bs[6144 + tid * 8]);
    __syncthreads();
    #pragma unroll
    for (int sub = 0; sub < 2; sub++) {
      int base = sub * 4096;
      sh8 af[4], bfr[4];
      #pragma unroll
      for (int mi = 0; mi < 4; mi++)
        af[mi] = *(const sh8*)&As[base + (wm + mi * 16 + l15) * 32 + quad * 8];
      #pragma unroll
      for (int ni = 0; ni < 4; ni++)
        bfr[ni] = *(const sh8*)&Bs[base + (wn + ni * 16 + l15) * 32 + quad * 8];
      #pragma unroll
      for (int mi = 0; mi < 4; mi++)
        #pragma unroll
        for (int ni = 0; ni < 4; ni++)
          acc[mi][ni] = __builtin_amdgcn_mfma_f32_16x16x32_bf16(af[mi], bfr[ni], acc[mi][ni], 0, 0, 0);
    }
  }

  #pragma unroll
  for (int mi = 0; mi < 4; mi++) {
    #pragma unroll
    for (int ni = 0; ni < 4; ni++) {
      #pragma unroll
      for (int r = 0; r < 4; r++) {
        int grow = gy * 128 + wm + mi * 16 + quad * 4 + r;
        int gcol = gx * 128 + wn + ni * 16 + l15;
        float v = acc[mi][ni][r];
        if (EPI == 1) {
          int b = grow >> 10, s = grow & 1023;
          if (gcol < 512) {
            int h = gcol >> 6, dh = gcol & 63;
            qo[(((size_t)b * H_ + h) * S_ + s) * DH_ + dh] = f2h(v + bias0[gcol]);
          } else {
            int n2 = gcol - 512;
            int two = n2 >> 9, h = (n2 >> 6) & 7, dh = n2 & 63;
            float vv = v + bias1[n2];
            if (two == 0) ko_[(((size_t)b * H_ + h) * S_ + s) * DH_ + dh] = f2h(vv);
            else          vto[(((size_t)b * H_ + h) * DH_ + dh) * S_ + s] = f2h(vv);
          }
        } else {
          float vp = __shfl_xor(v, 1);
          if ((l15 & 1) == 0) {
            float a = v, b = vp;
            float gv = a / (1.f + __expf(-a)) * b;
            outU[(size_t)grow * (N >> 1) + (gcol >> 1)] = f2bf(gv);
          }
        }
      }
    }
  }
}

// ---------------- 128x64 GEMM for small-N layers (256 blocks, 8 MFMA/iter) ----------------
// EPI 2: +bias0 +auxF(fp32) -> outF
// EPI 4: +auxH(bf16) -> outF, fused per-column partial sums -> part (for instance norm)
template<int EPI>
__global__ __launch_bounds__(256) void gemm_n64(
    const u16* __restrict__ A, const u16* __restrict__ Bt,
    int M, int N, int K,
    const float* __restrict__ bias0, const float* __restrict__ auxF,
    const u16* __restrict__ auxH, float* __restrict__ outF,
    float* __restrict__ part)
{
  __shared__ u16 As[128 * 32];
  __shared__ u16 Bs[64 * 32];
  __shared__ float ss1[4][2][16], ss2[4][2][16];
  int tid = threadIdx.x;
  int gx = blockIdx.x, gy = blockIdx.y;
  int l = tid & 63, w = tid >> 6;
  int l15 = l & 15, quad = l >> 4;
  int wm = (w >> 1) * 64, wn = (w & 1) * 32;
  f32x4 acc[4][2] = {};

  const u16* Ag = A  + (size_t)(gy * 128 + (tid >> 2)) * K + (tid & 3) * 8;
  const u16* Bg = Bt + (size_t)(gx * 64  + (tid >> 2)) * K + (tid & 3) * 8;

  for (int ko = 0; ko < K; ko += 32) {
    __syncthreads();
    gl_lds16(Ag + ko,                  &As[tid * 8]);
    gl_lds16(Ag + (size_t)64 * K + ko, &As[2048 + tid * 8]);
    gl_lds16(Bg + ko,                  &Bs[tid * 8]);
    __syncthreads();
    sh8 af[4], bfr[2];
    #pragma unroll
    for (int mi = 0; mi < 4; mi++)
      af[mi] = *(const sh8*)&As[(wm + mi * 16 + l15) * 32 + quad * 8];
    #pragma unroll
    for (int ni = 0; ni < 2; ni++)
      bfr[ni] = *(const sh8*)&Bs[(wn + ni * 16 + l15) * 32 + quad * 8];
    #pragma unroll
    for (int mi = 0; mi < 4; mi++)
      #pragma unroll
      for (int ni = 0; ni < 2; ni++)
        acc[mi][ni] = __builtin_amdgcn_mfma_f32_16x16x32_bf16(af[mi], bfr[ni], acc[mi][ni], 0, 0, 0);
  }

  float cs1[2] = {0.f, 0.f}, cs2[2] = {0.f, 0.f};
  #pragma unroll
  for (int mi = 0; mi < 4; mi++) {
    #pragma unroll
    for (int ni = 0; ni < 2; ni++) {
      #pragma unroll
      for (int r = 0; r < 4; r++) {
        int grow = gy * 128 + wm + mi * 16 + quad * 4 + r;
        int gcol = gx * 64 + wn + ni * 16 + l15;
        float v = acc[mi][ni][r];
        if (EPI == 2) v += bias0[gcol] + auxF[(size_t)grow * N + gcol];
        else          v += bf2f(auxH[(size_t)grow * N + gcol]);
        outF[(size_t)grow * N + gcol] = v;
        if (EPI == 4) { cs1[ni] += v; cs2[ni] += v * v; }
      }
    }
  }
  if (EPI == 4) {
    #pragma unroll
    for (int ni = 0; ni < 2; ni++) {
      cs1[ni] += __shfl_xor(cs1[ni], 16); cs1[ni] += __shfl_xor(cs1[ni], 32);
      cs2[ni] += __shfl_xor(cs2[ni], 16); cs2[ni] += __shfl_xor(cs2[ni], 32);
    }
    if (l < 16) {
      ss1[w][0][l15] = cs1[0]; ss1[w][1][l15] = cs1[1];
      ss2[w][0][l15] = cs2[0]; ss2[w][1][l15] = cs2[1];
    }
    __syncthreads();
    if (tid < 64) {
      int wsel = (tid >> 5) & 1, ni = (tid >> 4) & 1, cl = tid & 15;
      float s1 = ss1[wsel][ni][cl] + ss1[wsel + 2][ni][cl];
      float s2 = ss2[wsel][ni][cl] + ss2[wsel + 2][ni][cl];
      int col = gx * 64 + wsel * 32 + ni * 16 + cl;
      int b = gy >> 3, seg = gy & 7;
      float2 p; p.x = s1; p.y = s2;
      *(float2*)&part[((size_t)(b * 512 + col) * 8 + seg) * 2] = p;
    }
  }
}

// ---------------- sparse attention v9: hoisted K DMA + early V prefetch ----------------
// Z1 = sum e', Z2 = 1025 + S2/(2 Z1^2) (maskless Taylor softmax2, validated r8/r10).
#define RSTRIDE 1032                 // halves; c' row stride (2064 B)
#define STAGE_H (16 * RSTRIDE)       // staging region offset, halves
__global__ __launch_bounds__(256, 3) void attn_kernel(
    const u16* __restrict__ q, const u16* __restrict__ kk,
    const u16* __restrict__ vt, u16* __restrict__ attn)
{
  // c' 33,024B + staging 16,384B + sums 512B = 49,920B -> 3 blocks/CU
  __shared__ u16 scb[16 * RSTRIDE + 4 * 2048 + 256];
  float* sums = (float*)(scb + 16 * RSTRIDE + 4 * 2048);

  int tid = threadIdx.x;
  int l = tid & 63, w = tid >> 6;
  int l15 = l & 15, quad = l >> 4;
  int blk = blockIdx.x;
  // XCD-aware swizzle: 4 bh per XCD
  int xcd = blk & 7, li = blk >> 3;
  int bh = xcd * 4 + (li & 3);
  int r0 = (li >> 2) << 4;

  const u16* qb = q  + ((size_t)bh * S_ + r0) * DH_;
  const u16* kb = kk + (size_t)bh * S_ * DH_;
  const u16* vb = vt + (size_t)bh * DH_ * S_;

  int ws = STAGE_H + w * 2048;     // per-wave private staging base (halves)
  int lr = l >> 2, lc = l & 3;

  // hoist K slot0+slot1 DMAs: their L2 latency overlaps the q loads below
  {
    const u16* s0 = kb + (size_t)((w << 4) + lr) * DH_ + lc * 8;
    gl_lds16(s0,      &scb[ws + l * 8]);
    gl_lds16(s0 + 32, &scb[ws + 512 + l * 8]);
    const u16* s1 = kb + (size_t)(((1 << 6) | (w << 4)) + lr) * DH_ + lc * 8;
    gl_lds16(s1,      &scb[ws + 1024 + l * 8]);
    gl_lds16(s1 + 32, &scb[ws + 1536 + l * 8]);
  }

  h8 aq0 = *(const h8*)(qb + l15 * DH_ + quad * 8);
  h8 aq1 = *(const h8*)(qb + l15 * DH_ + 32 + quad * 8);

  // ---- phase A: K DMA-staged 2-deep; e' kept in registers; S1,S2 accumulated
  uint32_t kv[32];
  float S1 = 0.f, S2 = 0.f;
  #pragma unroll
  for (int i = 0; i < 16; i++) {
    if (i + 2 < 16) {
      int t0n = (((i + 2) << 2) | w) << 4;
      const u16* src = kb + (size_t)(t0n + lr) * DH_ + lc * 8;
      int sb = ws + ((i + 2) & 1) * 1024;
      gl_lds16(src,      &scb[sb + l * 8]);
      gl_lds16(src + 32, &scb[sb + 512 + l * 8]);
    }
    if (i + 2 < 16) { WAITVM(4); } else if (i + 1 < 16) { WAITVM(2); } else { WAITVM(0); }
    int sb = ws + (i & 1) * 1024;
    h8 bk0 = *(const h8*)&scb[sb + l15 * 32 + quad * 8];
    h8 bk1 = *(const h8*)&scb[sb + 512 + l15 * 32 + quad * 8];
    f32x4 s4 = {};
    s4 = __builtin_amdgcn_mfma_f32_16x16x32_f16(bk0, aq0, s4, 0, 0, 0);
    s4 = __builtin_amdgcn_mfma_f32_16x16x32_f16(bk1, aq1, s4, 0, 0, 0);
    float e0 = exp2f(fmaf(s4[0], 0.18033688f, -11.5415603f));   // exp(s/8 - 8)
    float e1 = exp2f(fmaf(s4[1], 0.18033688f, -11.5415603f));
    float e2 = exp2f(fmaf(s4[2], 0.18033688f, -11.5415603f));
    float e3 = exp2f(fmaf(s4[3], 0.18033688f, -11.5415603f));
    S1 += e0 + e1 + e2 + e3;
    S2 += e0 * e0 + e1 * e1 + e2 * e2 + e3 * e3;
    h2f p0; p0[0] = (_Float16)e0; p0[1] = (_Float16)e1;
    h2f p1; p1[0] = (_Float16)e2; p1[1] = (_Float16)e3;
    kv[2 * i]     = __builtin_bit_cast(uint32_t, p0);
    kv[2 * i + 1] = __builtin_bit_cast(uint32_t, p1);
  }
  // reduce across the 4 quads (same score row l15)
  S1 += __shfl_xor(S1, 16); S1 += __shfl_xor(S1, 32);
  S2 += __shfl_xor(S2, 16); S2 += __shfl_xor(S2, 32);
  if (l < 16) {
    sums[(w * 16 + l15) * 2]     = S1;
    sums[(w * 16 + l15) * 2 + 1] = S2;
  }
  __syncthreads();   // B1 (drains K DMAs; staging region reusable)

  // early V prefetch: overlaps the Horner/c'-store work below; drained by B2
  int n0 = w << 4;
  const u16* vsrc = vb + (size_t)(n0 + lr) * S_ + lc * 8;
  gl_lds16(vsrc,      &scb[ws + l * 8]);
  gl_lds16(vsrc + 32, &scb[ws + 512 + l * 8]);
  gl_lds16(vsrc + 64, &scb[ws + 1024 + l * 8]);

  float Z1 = 0.f, S2t = 0.f;
  #pragma unroll
  for (int ww = 0; ww < 4; ww++) {
    Z1  += sums[(ww * 16 + l15) * 2];
    S2t += sums[(ww * 16 + l15) * 2 + 1];
  }
  float invZ1 = 1.0f / Z1;
  float Z2 = 1025.0f + 0.5f * S2t * invZ1 * invZ1;
  float invZ2 = 1.0f / Z2;

  // c' = exp(w)/Z2 via packed-f16 Horner; write to LDS in phase-A layout
  _Float16 izh = (_Float16)invZ1;
  h2f izv; izv[0] = izh; izv[1] = izh;
  _Float16 z2h = (_Float16)invZ2;
  h2f z2v; z2v[0] = z2h; z2v[1] = z2h;
  h2f onev; onev[0] = (_Float16)1.f; onev[1] = (_Float16)1.f;
  h2f c2v;  c2v[0] = (_Float16)0.5f; c2v[1] = (_Float16)0.5f;
  h2f c6v;  c6v[0] = (_Float16)(1.f/6.f); c6v[1] = (_Float16)(1.f/6.f);
  #pragma unroll
  for (int i = 0; i < 16; i++) {
    int t0 = ((i << 2) | w) << 4;
    uint2 ov;
    #pragma unroll
    for (int hwd = 0; hwd < 2; hwd++) {
      h2f e = __builtin_bit_cast(h2f, kv[2 * i + hwd]);
      h2f wv = e * izv;
      h2f p = wv * c6v + c2v;
      h2f qq = wv * p + onev;
      h2f cm1 = wv * qq;
      h2f cp = cm1 * z2v + z2v;
      (&ov.x)[hwd] = __builtin_bit_cast(uint32_t, cp);
    }
    *(uint2*)(scb + l15 * RSTRIDE + t0 + quad * 4) = ov;
  }
  __syncthreads();   // B2 (drains V prefetch too — slots 0..2 hot)

  // ---- phase E: o = c' @ V, V DMA-staged 4-deep (1 KB slots, per-wave private)
  const u16* crow = scb + l15 * RSTRIDE;
  f32x4 oacc = {};
  #pragma unroll
  for (int kt = 0; kt < 32; kt++) {
    if (kt + 3 < 32)
      gl_lds16(vsrc + (kt + 3) * 32, &scb[ws + ((kt + 3) & 3) * 512 + l * 8]);
    if (kt < 29) { WAITVM(3); } else if (kt == 29) { WAITVM(2); }
    else if (kt == 30) { WAITVM(1); } else { WAITVM(0); }
    h8 ca = *(const h8*)(crow + kt * 32 + quad * 8);
    h8 vv = *(const h8*)&scb[ws + (kt & 3) * 512 + l15 * 32 + quad * 8];
    oacc = __builtin_amdgcn_mfma_f32_16x16x32_f16(ca, vv, oacc, 0, 0, 0);
  }
  int b = bh >> 3, hh = bh & 7;
  #pragma unroll
  for (int r = 0; r < 4; r++) {
    int rr = quad * 4 + r;
    attn[((size_t)b * S_ + r0 + rr) * D_ + hh * DH_ + n0 + l15] = f2bf(oacc[r]);
  }
}

// ---------------- RMS norm over D per row: fp32 in, bf16 out ----------------
__global__ __launch_bounds__(128) void rms_kernel(const float* __restrict__ in,
                                                  const float* __restrict__ w,
                                                  u16* __restrict__ out) {
  int row = blockIdx.x;
  int tid = threadIdx.x;
  const float* r = in + (size_t)row * D_;
  float v0 = r[tid], v1 = r[tid + 128], v2 = r[tid + 256], v3 = r[tid + 384];
  float s = v0 * v0 + v1 * v1 + v2 * v2 + v3 * v3;
  #pragma unroll
  for (int d = 1; d < 64; d <<= 1) s += __shfl_xor(s, d);
  __shared__ float red[2];
  if ((tid & 63) == 0) red[tid >> 6] = s;
  __syncthreads();
  s = red[0] + red[1];
  float rs = rsqrtf(s * (1.0f / 512.0f) + 1e-6f);
  out[(size_t)row * D_ + tid      ] = f2bf(v0 * rs * w[tid      ]);
  out[(size_t)row * D_ + tid + 128] = f2bf(v1 * rs * w[tid + 128]);
  out[(size_t)row * D_ + tid + 256] = f2bf(v2 * rs * w[tid + 256]);
  out[(size_t)row * D_ + tid + 384] = f2bf(v3 * rs * w[tid + 384]);
}

// ---------------- instance norm: stage-2 (partials fused into FFN-down) + apply ----------------
__global__ __launch_bounds__(256) void inorm_stats2(const float* __restrict__ part,
                                                    float* __restrict__ stats) {
  int idx = blockIdx.x * 256 + threadIdx.x;   // (b*512+d), 2048 total
  float s1 = 0.f, s2 = 0.f;
  #pragma unroll
  for (int i = 0; i < 8; i++) {
    float2 p = *(const float2*)&part[((size_t)idx * 8 + i) * 2];
    s1 += p.x; s2 += p.y;
  }
  float m = s1 * (1.f / 1024.f);
  float var = s2 * (1.f / 1024.f) - m * m;
  stats[idx * 2]     = m;
  stats[idx * 2 + 1] = rsqrtf(var + 1e-5f);
}

__global__ __launch_bounds__(256) void inorm_apply(const float* __restrict__ y,
                                                   const float* __restrict__ stats,
                                                   const float* __restrict__ w,
                                                   const float* __restrict__ bias,
                                                   float* __restrict__ out) {
  int row = blockIdx.x;
  int b = row >> 10;
  int tid = threadIdx.x;
  #pragma unroll
  for (int i = 0; i < 2; i++) {
    int d = tid + i * 256;
    float m  = stats[((size_t)b * D_ + d) * 2];
    float rs = stats[((size_t)b * D_ + d) * 2 + 1];
    float v = y[(size_t)row * D_ + d];
    out[(size_t)row * D_ + d] = (v - m) * rs * w[d] + bias[d];
  }
}

// ---------------- launch ----------------
extern "C" void kernel_launch(void* const* d_in, const int* in_sizes, int n_in,
                              void* d_out, int out_size, void* d_ws, size_t ws_size,
                              hipStream_t stream) {
  const float* x    = (const float*)d_in[0];
  const float* Wq   = (const float*)d_in[1];
  const float* bq   = (const float*)d_in[2];
  const float* Wkv  = (const float*)d_in[3];
  const float* bkv  = (const float*)d_in[4];
  const float* Wo   = (const float*)d_in[5];
  const float* bo   = (const float*)d_in[6];
  const float* rmsw = (const float*)d_in[7];
  const float* l1   = (const float*)d_in[8];
  const float* l2   = (const float*)d_in[9];
  const float* l3   = (const float*)d_in[10];
  const float* inw  = (const float*)d_in[11];
  const float* inb  = (const float*)d_in[12];
  float* out = (float*)d_out;

  char* ws = (char*)d_ws;
  size_t off = 0;
  auto alloc = [&](size_t n) { char* p = ws + off; off += (n + 255) & ~(size_t)255; return p; };
  u16*  xb   = (u16*) alloc((size_t)M_ * D_ * 2);
  u16*  Wt1  = (u16*) alloc((size_t)1536 * 512 * 2);
  u16*  Wot  = (u16*) alloc((size_t)512 * 512 * 2);
  u16*  W12t = (u16*) alloc((size_t)3072 * 512 * 2);   // interleaved l1/l2
  u16*  l3t  = (u16*) alloc((size_t)512 * 1536 * 2);
  u16*  qb   = (u16*) alloc((size_t)M_ * D_ * 2);      // f16 [B,H,S,DH]
  u16*  kb   = (u16*) alloc((size_t)M_ * D_ * 2);      // f16 [B,H,S,DH]
  u16*  vtb  = (u16*) alloc((size_t)M_ * D_ * 2);      // f16 [B,H,DH,S]
  u16*  attn = (u16*) alloc((size_t)M_ * D_ * 2);      // bf16 [B,S,D]
  float* tmpF = (float*)alloc((size_t)M_ * D_ * 4);
  u16*  hhat = (u16*) alloc((size_t)M_ * D_ * 2);
  u16*  g    = (u16*) alloc((size_t)M_ * INNER_ * 2);
  float* part  = (float*)alloc((size_t)B_ * D_ * 8 * 2 * 4);
  float* stats = (float*)alloc((size_t)B_ * D_ * 2 * 4);

  prep_all<<<2880, 256, 0, stream>>>(Wq, Wkv, Wo, l1, l2, l3, x,
                                     Wt1, Wot, W12t, l3t, xb);

  gemm_bt<1><<<dim3(12, 32), 256, 0, stream>>>(xb, Wt1, M_, 1536, 512,
      bq, bkv, nullptr, qb, kb, vtb);

  attn_kernel<<<2048, 256, 0, stream>>>(qb, kb, vtb, attn);

  gemm_n64<2><<<dim3(8, 32), 256, 0, stream>>>(attn, Wot, M_, 512, 512,
      bo, x, nullptr, tmpF, nullptr);

  rms_kernel<<<4096, 128, 0, stream>>>(tmpF, rmsw, hhat);

  // FFN up + silu fused: writes g [M, 1536] directly
  gemm_bt<3><<<dim3(24, 32), 256, 0, stream>>>(hhat, W12t, M_, 3072, 512,
      nullptr, nullptr, g, nullptr, nullptr, nullptr);

  // FFN down + residual + fused instance-norm partial sums
  gemm_n64<4><<<dim3(8, 32), 256, 0, stream>>>(g, l3t, M_, 512, 1536,
      nullptr, nullptr, hhat, tmpF, part);

  inorm_stats2<<<8, 256, 0, stream>>>(part, stats);
  inorm_apply<<<4096, 256, 0, stream>>>(tmpF, stats, inw, inb, out);
}